// Round 1
// baseline (888.672 us; speedup 1.0000x reference)
//
#include <hip/hip_runtime.h>
#include <math.h>

#define KM 16
#define KS 64
#define TWO_PI_F 6.283185307179586477f

__global__ __launch_bounds__(256)
void mobius_spline_kernel(const float* __restrict__ r_in,
                          const float* __restrict__ z_in,
                          const float* __restrict__ theta_w,
                          const float* __restrict__ theta_h,
                          const float* __restrict__ theta_d,
                          const float* __restrict__ W1,
                          const float* __restrict__ b1,
                          const float* __restrict__ W2,
                          const float* __restrict__ b2,
                          const float* __restrict__ W3,
                          const float* __restrict__ b3,
                          float* __restrict__ out,
                          int n)
{
    // LDS only for the spline tables (per-thread non-uniform index).
    // All MLP weights are read straight from global with WAVE-UNIFORM indices
    // -> compiler emits s_load (scalar pipe + K$), zero LDS/VALU-pipe cost.
    __shared__ float sxk[KS + 1], syk[KS + 1], sdk[KS + 1];
    __shared__ float stmp[2 * KS];

    const int tid = threadIdx.x;

    if (tid < 64) {  // exactly wave 0: spline tables
        float vw = theta_w[tid];
        float vh = theta_h[tid];
        float mw = vw, mh = vh;
        #pragma unroll
        for (int off = 32; off > 0; off >>= 1) {
            mw = fmaxf(mw, __shfl_xor(mw, off));
            mh = fmaxf(mh, __shfl_xor(mh, off));
        }
        const float ew = expf(vw - mw);
        const float eh = expf(vh - mh);
        float sumw = ew, sumh = eh;
        #pragma unroll
        for (int off = 32; off > 0; off >>= 1) {
            sumw += __shfl_xor(sumw, off);
            sumh += __shfl_xor(sumh, off);
        }
        stmp[tid]      = ew / sumw * 2.0f;   // width
        stmp[KS + tid] = eh / sumh * 2.0f;   // height

        if (tid < KS - 1) {
            const float x = theta_d[tid];
            const float sp = (x > 20.0f) ? x : log1pf(expf(x));
            sdk[1 + tid] = sp + 0.001f;
        }
        if (tid == 0) { sdk[0] = 1.0f; sdk[KS] = 1.0f; }
    }
    __syncthreads();
    if (tid == 0) {  // sequential cumsum matches jnp.cumsum accumulation order
        float cx = -1.0f, cy = -1.0f;
        sxk[0] = -1.0f; syk[0] = -1.0f;
        #pragma unroll 1
        for (int i = 0; i < KS; i++) {
            cx += stmp[i];
            cy += stmp[KS + i];
            sxk[i + 1] = cx;
            syk[i + 1] = cy;
        }
    }
    __syncthreads();

    const int idx = blockIdx.x * 256 + tid;
    if (idx >= n) return;

    const float rv = r_in[idx];
    const float zz = z_in[idx];

    // ---------------- spline ----------------
    int lo = 0, hi = KS + 1;
    while (lo < hi) {
        const int mid = (lo + hi) >> 1;
        if (sxk[mid] < rv) lo = mid + 1; else hi = mid;
    }
    int k = lo;
    k = (k == 0) ? 1 : k;
    k = (k == KS + 1) ? KS : k;
    k -= 1;
    const float x_k = sxk[k], x_nk = sxk[k + 1];
    const float y_k = syk[k], y_nk = syk[k + 1];
    const float d_k = sdk[k], d_nk = sdk[k + 1];
    const float dxk = x_nk - x_k;
    const float s_k = (y_nk - y_k) / dxk;
    const float eps = (rv - x_k) / dxk;
    const float ome = 1.0f - eps;
    const float den = s_k + (d_nk + d_k - 2.0f * s_k) * eps * ome;
    const float tr  = y_k + (y_nk - y_k) * (s_k * eps * eps + d_k * eps * ome) / den;
    const float dtr = s_k * s_k * (d_nk * eps * eps + 2.0f * s_k * eps * ome + d_k * ome * ome)
                      / (den * den);

    // ---------------- MLP phase 1: h2 = relu(h1 @ W2 + b2) ----------------
    // Outer-product order: h1_j computed on the fly (never stored as array).
    // h2[] is indexed ONLY with compile-time constants everywhere in this
    // kernel (all consuming loops fully unrolled) -> SROA promotes it to
    // 64 VGPRs instead of scratch. The previous version runtime-indexed it
    // in phase 2, demoting the whole array to scratch (~860 MB of HBM-visible
    // spill traffic per dispatch, VGPR_Count=40).
    float h2[64];
    #pragma unroll
    for (int i = 0; i < 64; i++) h2[i] = b2[i];          // uniform -> s_load

    #pragma unroll 2
    for (int j = 0; j < 64; j++) {
        const float h1j = fmaxf(fmaf(rv, W1[j], b1[j]), 0.0f);  // uniform s_loads
        const float* __restrict__ w2row = &W2[j * 64];          // row-major, natural
        #pragma unroll
        for (int i = 0; i < 64; i++)
            h2[i] = fmaf(h1j, w2row[i], h2[i]);                 // v_fmac v,s,v
    }
    #pragma unroll
    for (int i = 0; i < 64; i++) h2[i] = fmaxf(h2[i], 0.0f);

    // ---------------- MLP phase 2 + mobius, chunked to cap live registers ----
    // chunk 0: theta[0:16]  (softmax logits -> keep)
    float th0[16];
    #pragma unroll
    for (int q = 0; q < 16; q++) th0[q] = b3[q];
    #pragma unroll
    for (int i = 0; i < 64; i++) {                       // FULL unroll: h2[i] stays compile-time
        const float hv = h2[i];
        const float* __restrict__ w3r = &W3[i * 48];
        #pragma unroll
        for (int q = 0; q < 16; q++) th0[q] = fmaf(hv, w3r[q], th0[q]);
    }
    float mx = th0[0];
    #pragma unroll
    for (int q = 1; q < 16; q++) mx = fmaxf(mx, th0[q]);

    float cz, sz2;
    sincosf(zz, &sz2, &cz);
    float wsum = 0.0f, tsum = 0.0f, dsum = 0.0f;

    // chunks 1,2: theta[16:32], theta[32:48] = w-pairs; consume immediately
    #pragma unroll 1
    for (int c = 1; c < 3; c++) {
        float acc[16];
        #pragma unroll
        for (int q = 0; q < 16; q++) acc[q] = b3[c * 16 + q];
        #pragma unroll
        for (int i = 0; i < 64; i++) {                   // FULL unroll: h2[i] compile-time
            const float hv = h2[i];
            const float* __restrict__ w3r = &W3[i * 48 + c * 16];
            #pragma unroll
            for (int q = 0; q < 16; q++) acc[q] = fmaf(hv, w3r[q], acc[q]);
        }
        const int qbase = (c - 1) * 8;
        #pragma unroll
        for (int qq = 0; qq < 8; qq++) {
            const int q = qbase + qq;           // mobius term index, same order as ref
            const float rwx = acc[2 * qq];
            const float rwy = acc[2 * qq + 1];
            const float nrm = sqrtf(rwx * rwx + rwy * rwy);
            const float scl = 0.99f / (1.0f + nrm);
            const float wx = scl * rwx, wy = scl * rwy;
            const float wn2 = wx * wx + wy * wy;
            const float omw = 1.0f - wn2;
            // h_map(zv, w)
            const float dzx = cz - wx, dzy = sz2 - wy;
            const float dn2z = dzx * dzx + dzy * dzy;
            const float cf = omw / dn2z;
            const float hzx = cf * dzx - wx;
            const float hzy = cf * dzy - wy;
            // h_map((1,0), w)
            const float d0x = 1.0f - wx, d0y = -wy;
            const float dn20 = d0x * d0x + d0y * d0y;
            const float c0 = omw / dn20;
            const float h0x = c0 * d0x - wx;
            const float h0y = c0 * d0y - wy;
            const float rad = atan2f(hzy, hzx);
            const float shf = atan2f(h0y, h0x);
            float tx = rad - shf;
            tx = (tx >= 0.0f) ? tx : tx + TWO_PI_F;
            const float ew = expf(th0[q] - mx);
            wsum += ew;
            tsum += ew * tx;
            // |dh| = cf exactly: dh = cf*(dz - 2u(u.dz)) is a reflection of unit dz
            dsum += ew * cf;
        }
    }

    const float inv = 1.0f / wsum;
    const float tz  = tsum * inv;
    const float dtz = dsum * inv;
    const float ldj = logf(dtr) + logf(dtz);

    out[idx]         = tr;
    out[n + idx]     = tz;
    out[2 * n + idx] = ldj;
}

extern "C" void kernel_launch(void* const* d_in, const int* in_sizes, int n_in,
                              void* d_out, int out_size, void* d_ws, size_t ws_size,
                              hipStream_t stream) {
    const int n = in_sizes[0];  // 1,000,000
    const int blocks = (n + 255) / 256;
    hipLaunchKernelGGL(mobius_spline_kernel, dim3(blocks), dim3(256), 0, stream,
                       (const float*)d_in[0], (const float*)d_in[1],
                       (const float*)d_in[2], (const float*)d_in[3],
                       (const float*)d_in[4], (const float*)d_in[5],
                       (const float*)d_in[6], (const float*)d_in[7],
                       (const float*)d_in[8], (const float*)d_in[9],
                       (const float*)d_in[10],
                       (float*)d_out, n);
}

// Round 2
// 524.105 us; speedup vs baseline: 1.6956x; 1.6956x over previous
//
#include <hip/hip_runtime.h>
#include <math.h>

#define KM 16
#define KS 64
#define TWO_PI_F 6.283185307179586477f

__global__ __launch_bounds__(256, 4)
void mobius_spline_kernel(const float* __restrict__ r_in,
                          const float* __restrict__ z_in,
                          const float* __restrict__ theta_w,
                          const float* __restrict__ theta_h,
                          const float* __restrict__ theta_d,
                          const float* __restrict__ W1,
                          const float* __restrict__ b1,
                          const float* __restrict__ W2,
                          const float* __restrict__ b2,
                          const float* __restrict__ W3,
                          const float* __restrict__ b3,
                          float* __restrict__ out,
                          int n)
{
    // LDS only for the spline tables (per-thread non-uniform index).
    __shared__ float sxk[KS + 1], syk[KS + 1], sdk[KS + 1];
    __shared__ float stmp[2 * KS];

    const int tid = threadIdx.x;

    if (tid < 64) {  // exactly wave 0: spline tables
        float vw = theta_w[tid];
        float vh = theta_h[tid];
        float mw = vw, mh = vh;
        #pragma unroll
        for (int off = 32; off > 0; off >>= 1) {
            mw = fmaxf(mw, __shfl_xor(mw, off));
            mh = fmaxf(mh, __shfl_xor(mh, off));
        }
        const float ew = expf(vw - mw);
        const float eh = expf(vh - mh);
        float sumw = ew, sumh = eh;
        #pragma unroll
        for (int off = 32; off > 0; off >>= 1) {
            sumw += __shfl_xor(sumw, off);
            sumh += __shfl_xor(sumh, off);
        }
        stmp[tid]      = ew / sumw * 2.0f;   // width
        stmp[KS + tid] = eh / sumh * 2.0f;   // height

        if (tid < KS - 1) {
            const float x = theta_d[tid];
            const float sp = (x > 20.0f) ? x : log1pf(expf(x));
            sdk[1 + tid] = sp + 0.001f;
        }
        if (tid == 0) { sdk[0] = 1.0f; sdk[KS] = 1.0f; }
    }
    __syncthreads();
    if (tid == 0) {  // sequential cumsum matches jnp.cumsum accumulation order
        float cx = -1.0f, cy = -1.0f;
        sxk[0] = -1.0f; syk[0] = -1.0f;
        #pragma unroll 1
        for (int i = 0; i < KS; i++) {
            cx += stmp[i];
            cy += stmp[KS + i];
            sxk[i + 1] = cx;
            syk[i + 1] = cy;
        }
    }
    __syncthreads();

    const int idx = blockIdx.x * 256 + tid;
    if (idx >= n) return;

    const float rv = r_in[idx];
    const float zz = z_in[idx];

    // ---------------- spline ----------------
    int lo = 0, hi = KS + 1;
    while (lo < hi) {
        const int mid = (lo + hi) >> 1;
        if (sxk[mid] < rv) lo = mid + 1; else hi = mid;
    }
    int k = lo;
    k = (k == 0) ? 1 : k;
    k = (k == KS + 1) ? KS : k;
    k -= 1;
    const float x_k = sxk[k], x_nk = sxk[k + 1];
    const float y_k = syk[k], y_nk = syk[k + 1];
    const float d_k = sdk[k], d_nk = sdk[k + 1];
    const float dxk = x_nk - x_k;
    const float s_k = (y_nk - y_k) / dxk;
    const float eps = (rv - x_k) / dxk;
    const float ome = 1.0f - eps;
    const float den = s_k + (d_nk + d_k - 2.0f * s_k) * eps * ome;
    const float tr  = y_k + (y_nk - y_k) * (s_k * eps * eps + d_k * eps * ome) / den;
    const float dtr = s_k * s_k * (d_nk * eps * eps + 2.0f * s_k * eps * ome + d_k * ome * ome)
                      / (den * den);

    // ---------------- MLP phase 1: h2 = relu(h1 @ W2 + b2) ----------------
    // h2[] is indexed ONLY with compile-time constants (this loop's inner
    // unroll, and phase 2's fully-unrolled i-loop) -> SROA keeps it in 64
    // VGPRs. The j-loop stays a runtime loop (small code; it never indexes h2).
    float h2[64];
    #pragma unroll
    for (int i = 0; i < 64; i++) h2[i] = b2[i];          // uniform -> s_load

    #pragma unroll 2
    for (int j = 0; j < 64; j++) {
        const float h1j = fmaxf(fmaf(rv, W1[j], b1[j]), 0.0f);  // uniform s_loads
        const float* __restrict__ w2row = &W2[j * 64];
        #pragma unroll
        for (int i = 0; i < 64; i++)
            h2[i] = fmaf(h1j, w2row[i], h2[i]);                 // v_fmac v,s,v
    }
    #pragma unroll
    for (int i = 0; i < 64; i++) h2[i] = fmaxf(h2[i], 0.0f);

    // ---------------- MLP phase 2 + mobius: per-q fused loop ----------------
    // q is a RUNTIME loop (code stays ~2 KB, I$-resident — round-1's full
    // unroll was ~36 KB of straight-line code and thrashed the 32 KB I$).
    // Inside, the i-loop is fully unrolled so h2[i] is compile-time.
    // Accumulators are SCALARS (th, wxr, wyr) — no runtime-indexed arrays,
    // nothing demotes to scratch. Softmax is done ONLINE (running max m_run,
    // rescale wsum/tsum/dsum by exp(m_old - m_new)); mathematically identical
    // to the two-pass reference softmax.
    float cz, sz2;
    sincosf(zz, &sz2, &cz);

    float m_run = -INFINITY;
    float wsum = 0.0f, tsum = 0.0f, dsum = 0.0f;

    #pragma unroll 1
    for (int q = 0; q < 16; q++) {
        // three W3 columns for this q: logit col q, w-pair cols 16+2q, 17+2q.
        // All addresses wave-uniform (q uniform) -> scalar loads.
        float th  = b3[q];
        float wxr = b3[16 + 2 * q];
        float wyr = b3[17 + 2 * q];
        const float* __restrict__ w3th = W3 + q;
        const float* __restrict__ w3wp = W3 + 16 + 2 * q;
        #pragma unroll
        for (int i = 0; i < 64; i++) {
            const float hv = h2[i];                // compile-time index ✓
            th  = fmaf(hv, w3th[i * 48],     th);
            wxr = fmaf(hv, w3wp[i * 48],     wxr);
            wyr = fmaf(hv, w3wp[i * 48 + 1], wyr);
        }

        // ---- mobius term q (same math/order as reference) ----
        const float nrm = sqrtf(wxr * wxr + wyr * wyr);
        const float scl = 0.99f / (1.0f + nrm);
        const float wx = scl * wxr, wy = scl * wyr;
        const float wn2 = wx * wx + wy * wy;
        const float omw = 1.0f - wn2;
        // h_map(zv, w)
        const float dzx = cz - wx, dzy = sz2 - wy;
        const float dn2z = dzx * dzx + dzy * dzy;
        const float cf = omw / dn2z;
        const float hzx = cf * dzx - wx;
        const float hzy = cf * dzy - wy;
        // h_map((1,0), w)
        const float d0x = 1.0f - wx, d0y = -wy;
        const float dn20 = d0x * d0x + d0y * d0y;
        const float c0 = omw / dn20;
        const float h0x = c0 * d0x - wx;
        const float h0y = c0 * d0y - wy;
        const float rad = atan2f(hzy, hzx);
        const float shf = atan2f(h0y, h0x);
        float tx = rad - shf;
        tx = (tx >= 0.0f) ? tx : tx + TWO_PI_F;

        // ---- online softmax accumulate ----
        const float m_new = fmaxf(m_run, th);
        const float rs = expf(m_run - m_new);   // == 1.0f when max unchanged
        wsum *= rs; tsum *= rs; dsum *= rs;
        m_run = m_new;
        const float ew = expf(th - m_run);
        wsum += ew;
        tsum += ew * tx;
        // |dh| = cf exactly: dh = cf*(dz - 2u(u.dz)) is a reflection of unit dz
        dsum += ew * cf;
    }

    const float inv = 1.0f / wsum;
    const float tz  = tsum * inv;
    const float dtz = dsum * inv;
    const float ldj = logf(dtr) + logf(dtz);

    out[idx]         = tr;
    out[n + idx]     = tz;
    out[2 * n + idx] = ldj;
}

extern "C" void kernel_launch(void* const* d_in, const int* in_sizes, int n_in,
                              void* d_out, int out_size, void* d_ws, size_t ws_size,
                              hipStream_t stream) {
    const int n = in_sizes[0];  // 1,000,000
    const int blocks = (n + 255) / 256;
    hipLaunchKernelGGL(mobius_spline_kernel, dim3(blocks), dim3(256), 0, stream,
                       (const float*)d_in[0], (const float*)d_in[1],
                       (const float*)d_in[2], (const float*)d_in[3],
                       (const float*)d_in[4], (const float*)d_in[5],
                       (const float*)d_in[6], (const float*)d_in[7],
                       (const float*)d_in[8], (const float*)d_in[9],
                       (const float*)d_in[10],
                       (float*)d_out, n);
}

// Round 3
// 358.364 us; speedup vs baseline: 2.4798x; 1.4625x over previous
//
#include <hip/hip_runtime.h>
#include <math.h>

#define KM 16
#define KS 64
#define TWO_PI_F 6.283185307179586477f

// NOTE: plain __launch_bounds__(256) — NO min-waves arg. Round 2 used
// (256, 4) which caps the allocator at 128 VGPRs; this kernel needs ~148
// with h2[64] register-promoted, so the cap silently spilled the whole
// array to scratch (VGPR_Count dropped to 64, 248 MB of HBM leak-through).
__global__ __launch_bounds__(256)
void mobius_spline_kernel(const float* __restrict__ r_in,
                          const float* __restrict__ z_in,
                          const float* __restrict__ theta_w,
                          const float* __restrict__ theta_h,
                          const float* __restrict__ theta_d,
                          const float* __restrict__ W1,
                          const float* __restrict__ b1,
                          const float* __restrict__ W2,
                          const float* __restrict__ b2,
                          const float* __restrict__ W3,
                          const float* __restrict__ b3,
                          float* __restrict__ out,
                          int n)
{
    // LDS only for the spline tables (per-thread non-uniform index).
    __shared__ float sxk[KS + 1], syk[KS + 1], sdk[KS + 1];
    __shared__ float stmp[2 * KS];

    const int tid = threadIdx.x;

    if (tid < 64) {  // exactly wave 0: spline tables
        float vw = theta_w[tid];
        float vh = theta_h[tid];
        float mw = vw, mh = vh;
        #pragma unroll
        for (int off = 32; off > 0; off >>= 1) {
            mw = fmaxf(mw, __shfl_xor(mw, off));
            mh = fmaxf(mh, __shfl_xor(mh, off));
        }
        const float ew = expf(vw - mw);
        const float eh = expf(vh - mh);
        float sumw = ew, sumh = eh;
        #pragma unroll
        for (int off = 32; off > 0; off >>= 1) {
            sumw += __shfl_xor(sumw, off);
            sumh += __shfl_xor(sumh, off);
        }
        stmp[tid]      = ew / sumw * 2.0f;   // width
        stmp[KS + tid] = eh / sumh * 2.0f;   // height

        if (tid < KS - 1) {
            const float x = theta_d[tid];
            const float sp = (x > 20.0f) ? x : log1pf(expf(x));
            sdk[1 + tid] = sp + 0.001f;
        }
        if (tid == 0) { sdk[0] = 1.0f; sdk[KS] = 1.0f; }
    }
    __syncthreads();
    if (tid == 0) {  // sequential cumsum matches jnp.cumsum accumulation order
        float cx = -1.0f, cy = -1.0f;
        sxk[0] = -1.0f; syk[0] = -1.0f;
        #pragma unroll 1
        for (int i = 0; i < KS; i++) {
            cx += stmp[i];
            cy += stmp[KS + i];
            sxk[i + 1] = cx;
            syk[i + 1] = cy;
        }
    }
    __syncthreads();

    const int idx = blockIdx.x * 256 + tid;
    if (idx >= n) return;

    const float rv = r_in[idx];
    const float zz = z_in[idx];

    // ---------------- spline ----------------
    int lo = 0, hi = KS + 1;
    while (lo < hi) {
        const int mid = (lo + hi) >> 1;
        if (sxk[mid] < rv) lo = mid + 1; else hi = mid;
    }
    int k = lo;
    k = (k == 0) ? 1 : k;
    k = (k == KS + 1) ? KS : k;
    k -= 1;
    const float x_k = sxk[k], x_nk = sxk[k + 1];
    const float y_k = syk[k], y_nk = syk[k + 1];
    const float d_k = sdk[k], d_nk = sdk[k + 1];
    const float dxk = x_nk - x_k;
    const float s_k = (y_nk - y_k) / dxk;
    const float eps = (rv - x_k) / dxk;
    const float ome = 1.0f - eps;
    const float den = s_k + (d_nk + d_k - 2.0f * s_k) * eps * ome;
    const float tr  = y_k + (y_nk - y_k) * (s_k * eps * eps + d_k * eps * ome) / den;
    const float dtr = s_k * s_k * (d_nk * eps * eps + 2.0f * s_k * eps * ome + d_k * ome * ome)
                      / (den * den);

    // ---------------- MLP phase 1: h2 = relu(h1 @ W2 + b2) ----------------
    // h2[] is indexed ONLY with compile-time constants (this loop's inner
    // unroll, and phase 2's fully-unrolled i-loop) -> SROA keeps it in 64
    // VGPRs. The j-loop stays a runtime loop (small code; it never indexes h2).
    float h2[64];
    #pragma unroll
    for (int i = 0; i < 64; i++) h2[i] = b2[i];          // uniform -> s_load

    #pragma unroll 2
    for (int j = 0; j < 64; j++) {
        const float h1j = fmaxf(fmaf(rv, W1[j], b1[j]), 0.0f);  // uniform s_loads
        const float* __restrict__ w2row = &W2[j * 64];
        #pragma unroll
        for (int i = 0; i < 64; i++)
            h2[i] = fmaf(h1j, w2row[i], h2[i]);                 // v_fmac v,s,v
    }
    #pragma unroll
    for (int i = 0; i < 64; i++) h2[i] = fmaxf(h2[i], 0.0f);

    // ---------------- MLP phase 2 + mobius: per-q fused loop ----------------
    // q is a RUNTIME loop (code stays ~2 KB, I$-resident — round-1's full
    // unroll was ~36 KB of straight-line code and thrashed the 32 KB I$).
    // Inside, the i-loop is fully unrolled so h2[i] is compile-time.
    // Accumulators are SCALARS (th, wxr, wyr) — no runtime-indexed arrays,
    // nothing demotes to scratch. Softmax is done ONLINE (running max m_run,
    // rescale wsum/tsum/dsum by exp(m_old - m_new)); mathematically identical
    // to the two-pass reference softmax.
    float cz, sz2;
    sincosf(zz, &sz2, &cz);

    float m_run = -INFINITY;
    float wsum = 0.0f, tsum = 0.0f, dsum = 0.0f;

    #pragma unroll 1
    for (int q = 0; q < 16; q++) {
        // three W3 columns for this q: logit col q, w-pair cols 16+2q, 17+2q.
        // All addresses wave-uniform (q uniform) -> scalar loads.
        float th  = b3[q];
        float wxr = b3[16 + 2 * q];
        float wyr = b3[17 + 2 * q];
        const float* __restrict__ w3th = W3 + q;
        const float* __restrict__ w3wp = W3 + 16 + 2 * q;
        #pragma unroll
        for (int i = 0; i < 64; i++) {
            const float hv = h2[i];                // compile-time index ✓
            th  = fmaf(hv, w3th[i * 48],     th);
            wxr = fmaf(hv, w3wp[i * 48],     wxr);
            wyr = fmaf(hv, w3wp[i * 48 + 1], wyr);
        }

        // ---- mobius term q (same math/order as reference) ----
        const float nrm = sqrtf(wxr * wxr + wyr * wyr);
        const float scl = 0.99f / (1.0f + nrm);
        const float wx = scl * wxr, wy = scl * wyr;
        const float wn2 = wx * wx + wy * wy;
        const float omw = 1.0f - wn2;
        // h_map(zv, w)
        const float dzx = cz - wx, dzy = sz2 - wy;
        const float dn2z = dzx * dzx + dzy * dzy;
        const float cf = omw / dn2z;
        const float hzx = cf * dzx - wx;
        const float hzy = cf * dzy - wy;
        // h_map((1,0), w)
        const float d0x = 1.0f - wx, d0y = -wy;
        const float dn20 = d0x * d0x + d0y * d0y;
        const float c0 = omw / dn20;
        const float h0x = c0 * d0x - wx;
        const float h0y = c0 * d0y - wy;
        const float rad = atan2f(hzy, hzx);
        const float shf = atan2f(h0y, h0x);
        float tx = rad - shf;
        tx = (tx >= 0.0f) ? tx : tx + TWO_PI_F;

        // ---- online softmax accumulate ----
        const float m_new = fmaxf(m_run, th);
        const float rs = expf(m_run - m_new);   // == 1.0f when max unchanged
        wsum *= rs; tsum *= rs; dsum *= rs;
        m_run = m_new;
        const float ew = expf(th - m_run);
        wsum += ew;
        tsum += ew * tx;
        // |dh| = cf exactly: dh = cf*(dz - 2u(u.dz)) is a reflection of unit dz
        dsum += ew * cf;
    }

    const float inv = 1.0f / wsum;
    const float tz  = tsum * inv;
    const float dtz = dsum * inv;
    const float ldj = logf(dtr) + logf(dtz);

    out[idx]         = tr;
    out[n + idx]     = tz;
    out[2 * n + idx] = ldj;
}

extern "C" void kernel_launch(void* const* d_in, const int* in_sizes, int n_in,
                              void* d_out, int out_size, void* d_ws, size_t ws_size,
                              hipStream_t stream) {
    const int n = in_sizes[0];  // 1,000,000
    const int blocks = (n + 255) / 256;
    hipLaunchKernelGGL(mobius_spline_kernel, dim3(blocks), dim3(256), 0, stream,
                       (const float*)d_in[0], (const float*)d_in[1],
                       (const float*)d_in[2], (const float*)d_in[3],
                       (const float*)d_in[4], (const float*)d_in[5],
                       (const float*)d_in[6], (const float*)d_in[7],
                       (const float*)d_in[8], (const float*)d_in[9],
                       (const float*)d_in[10],
                       (float*)d_out, n);
}

// Round 4
// 225.382 us; speedup vs baseline: 3.9430x; 1.5900x over previous
//
#include <hip/hip_runtime.h>
#include <math.h>

#define KM 16
#define KS 64
#define TWO_PI_F 6.283185307179586477f

// Workspace float-offset layout (written by precompute_kernel, read by main):
//   [0..64]      sxk   (65)  spline x knots
//   [65..129]    syk   (65)  spline y knots
//   [130..194]   sdk   (65)  spline derivs
//   [195..258]   sknot (64)  sorted relu-toggle knots of phase-1 MLP
//   [259..4483]  A     (65*65, stride 65, col 64 unused)  h2_i = relu(A[v][i]*r + B[v][i])
//   [4484..8708] B     (65*65)
#define WS_SXK   0
#define WS_SYK   65
#define WS_SDK   130
#define WS_KNOT  195
#define WS_A     259
#define WS_B     (259 + 4225)
#define WS_TOTAL (259 + 2 * 4225)

// ---------------------------------------------------------------------------
// Kernel A: one block, runs once. Computes spline tables AND the piecewise-
// linear factorization of the first two MLP layers.
//   h1_j(r) = relu(W1_j r + b1_j) toggles at knot t_j = -b1_j/W1_j.
//   Within interval v of the sorted knots, h2_i = relu(A_i(v) r + B_i(v)),
//   A_i(v) = sum_{j active} W1_j W2_ji,  B_i(v) = b2_i + sum_{j active} b1_j W2_ji.
//   Built as base (interval 0: active = {j: W1_j<0}) + per-knot toggle deltas,
//   prefix-summed over rows.
// ---------------------------------------------------------------------------
__global__ __launch_bounds__(256)
void precompute_kernel(const float* __restrict__ theta_w,
                       const float* __restrict__ theta_h,
                       const float* __restrict__ theta_d,
                       const float* __restrict__ W1,
                       const float* __restrict__ b1,
                       const float* __restrict__ W2,
                       const float* __restrict__ b2,
                       float* __restrict__ ws)
{
    __shared__ float sA[65 * 65], sB[65 * 65];
    __shared__ float sxk[KS + 1], syk[KS + 1], sdk[KS + 1];
    __shared__ float stmp[2 * KS];
    __shared__ float tj[KS];
    __shared__ int   rnk[KS];
    __shared__ float sknot[KS];

    const int tid = threadIdx.x;

    // ---- spline tables (same math as before) ----
    if (tid < 64) {
        float vw = theta_w[tid];
        float vh = theta_h[tid];
        float mw = vw, mh = vh;
        #pragma unroll
        for (int off = 32; off > 0; off >>= 1) {
            mw = fmaxf(mw, __shfl_xor(mw, off));
            mh = fmaxf(mh, __shfl_xor(mh, off));
        }
        const float ew = expf(vw - mw);
        const float eh = expf(vh - mh);
        float sumw = ew, sumh = eh;
        #pragma unroll
        for (int off = 32; off > 0; off >>= 1) {
            sumw += __shfl_xor(sumw, off);
            sumh += __shfl_xor(sumh, off);
        }
        stmp[tid]      = ew / sumw * 2.0f;
        stmp[KS + tid] = eh / sumh * 2.0f;
        if (tid < KS - 1) {
            const float x = theta_d[tid];
            const float sp = (x > 20.0f) ? x : log1pf(expf(x));
            sdk[1 + tid] = sp + 0.001f;
        }
        if (tid == 0) { sdk[0] = 1.0f; sdk[KS] = 1.0f; }
    }
    __syncthreads();
    if (tid == 0) {  // sequential cumsum matches jnp.cumsum accumulation order
        float cx = -1.0f, cy = -1.0f;
        sxk[0] = -1.0f; syk[0] = -1.0f;
        #pragma unroll 1
        for (int i = 0; i < KS; i++) {
            cx += stmp[i];
            cy += stmp[KS + i];
            sxk[i + 1] = cx;
            syk[i + 1] = cy;
        }
    }
    __syncthreads();

    // ---- knots + ranks (lane j) ----
    if (tid < 64) {
        const float w1 = W1[tid];
        const float bb = b1[tid];
        tj[tid] = (w1 != 0.0f) ? (-bb / w1) : INFINITY;  // W1==0: constant feature, no knot
    }
    __syncthreads();
    if (tid < 64) {
        const float t = tj[tid];
        int rk = 0;
        #pragma unroll 1
        for (int k2 = 0; k2 < 64; k2++) {
            const float tk = tj[k2];
            rk += (tk < t || (tk == t && k2 < tid)) ? 1 : 0;
        }
        rnk[tid] = rk;
        sknot[rk] = t;     // distinct ranks -> permutation scatter
    }
    __syncthreads();

    // ---- base row + toggle-delta rows + in-place prefix (lane = output i) ----
    if (tid < 64) {
        const int i = tid;
        float baseA = 0.0f, baseB = b2[i];
        #pragma unroll 1
        for (int j = 0; j < 64; j++) {
            const float w1 = W1[j];
            const float bb = b1[j];
            const float w2 = W2[j * 64 + i];
            float dA, dB;
            if (w1 > 0.0f)      { dA =  w1 * w2; dB =  bb * w2; }
            else if (w1 < 0.0f) { dA = -w1 * w2; dB = -bb * w2;
                                  baseA += w1 * w2; baseB += bb * w2; }
            else                { dA = 0.0f;     dB = 0.0f;
                                  baseB += fmaxf(bb, 0.0f) * w2; }
            const int v = rnk[j] + 1;   // broadcast LDS read
            sA[v * 65 + i] = dA;
            sB[v * 65 + i] = dB;
        }
        sA[i] = baseA;
        sB[i] = baseB;
        float accA = baseA, accB = baseB;
        #pragma unroll 1
        for (int v = 1; v <= 64; v++) {
            accA += sA[v * 65 + i];
            accB += sB[v * 65 + i];
            sA[v * 65 + i] = accA;
            sB[v * 65 + i] = accB;
        }
    }
    __syncthreads();

    // ---- copy all tables to workspace ----
    for (int t2 = tid; t2 < 65; t2 += 256) {
        ws[WS_SXK + t2] = sxk[t2];
        ws[WS_SYK + t2] = syk[t2];
        ws[WS_SDK + t2] = sdk[t2];
    }
    for (int t2 = tid; t2 < 64; t2 += 256) ws[WS_KNOT + t2] = sknot[t2];
    for (int t2 = tid; t2 < 4225; t2 += 256) {
        ws[WS_A + t2] = sA[t2];
        ws[WS_B + t2] = sB[t2];
    }
}

// ---------------------------------------------------------------------------
// Kernel B: main per-point kernel. No phase-1 GEMM: h2_i comes from the LDS
// A/B table (2 ds_read + fma + max per i), fused into the phase-2 loop.
// ---------------------------------------------------------------------------
__global__ __launch_bounds__(256)
void mobius_spline_kernel(const float* __restrict__ r_in,
                          const float* __restrict__ z_in,
                          const float* __restrict__ W3,
                          const float* __restrict__ b3,
                          const float* __restrict__ ws,
                          float* __restrict__ out,
                          int n)
{
    __shared__ float sxk[KS + 1], syk[KS + 1], sdk[KS + 1];
    __shared__ float sknot[KS];
    __shared__ float sA[65 * 65], sB[65 * 65];   // stride 65 (odd) -> banks spread

    const int tid = threadIdx.x;

    for (int t2 = tid; t2 < 65; t2 += 256) {
        sxk[t2] = ws[WS_SXK + t2];
        syk[t2] = ws[WS_SYK + t2];
        sdk[t2] = ws[WS_SDK + t2];
    }
    for (int t2 = tid; t2 < 64; t2 += 256) sknot[t2] = ws[WS_KNOT + t2];
    for (int t2 = tid; t2 < 4225; t2 += 256) {
        sA[t2] = ws[WS_A + t2];
        sB[t2] = ws[WS_B + t2];
    }
    __syncthreads();

    const int idx = blockIdx.x * 256 + tid;
    if (idx >= n) return;

    const float rv = r_in[idx];
    const float zz = z_in[idx];

    // ---------------- spline ----------------
    int lo = 0, hi = KS + 1;
    while (lo < hi) {
        const int mid = (lo + hi) >> 1;
        if (sxk[mid] < rv) lo = mid + 1; else hi = mid;
    }
    int k = lo;
    k = (k == 0) ? 1 : k;
    k = (k == KS + 1) ? KS : k;
    k -= 1;
    const float x_k = sxk[k], x_nk = sxk[k + 1];
    const float y_k = syk[k], y_nk = syk[k + 1];
    const float d_k = sdk[k], d_nk = sdk[k + 1];
    const float dxk = x_nk - x_k;
    const float s_k = (y_nk - y_k) / dxk;
    const float eps = (rv - x_k) / dxk;
    const float ome = 1.0f - eps;
    const float den = s_k + (d_nk + d_k - 2.0f * s_k) * eps * ome;
    const float tr  = y_k + (y_nk - y_k) * (s_k * eps * eps + d_k * eps * ome) / den;
    const float dtr = s_k * s_k * (d_nk * eps * eps + 2.0f * s_k * eps * ome + d_k * ome * ome)
                      / (den * den);

    // ---------------- interval of r among MLP knots ----------------
    int lo2 = 0, hi2 = KS;               // itv in [0, 64]
    while (lo2 < hi2) {
        const int mid = (lo2 + hi2) >> 1;
        if (sknot[mid] < rv) lo2 = mid + 1; else hi2 = mid;
    }
    const int abase = lo2 * 65;

    // ---------------- fused phase 2: theta = h2 @ W3 + b3 ----------------
    // h2_i recomputed per i from the table: no h2[64] register array at all.
    // 48 accumulators, all compile-time indexed (q-loops unrolled).
    float th[16], wx[16], wy[16];
    #pragma unroll
    for (int q = 0; q < 16; q++) {
        th[q] = b3[q];
        wx[q] = b3[16 + 2 * q];
        wy[q] = b3[17 + 2 * q];
    }

    #pragma unroll 4
    for (int i = 0; i < 64; i++) {
        const float hv = fmaxf(fmaf(rv, sA[abase + i], sB[abase + i]), 0.0f);
        const float* __restrict__ w3r = &W3[i * 48];   // contiguous row -> wide s_loads
        #pragma unroll
        for (int q = 0; q < 16; q++) {
            th[q] = fmaf(hv, w3r[q],          th[q]);
            wx[q] = fmaf(hv, w3r[16 + 2 * q], wx[q]);
            wy[q] = fmaf(hv, w3r[17 + 2 * q], wy[q]);
        }
    }

    // ---------------- softmax max ----------------
    float mx = th[0];
    #pragma unroll
    for (int q = 1; q < 16; q++) mx = fmaxf(mx, th[q]);

    float cz, sz;
    sincosf(zz, &sz, &cz);

    float wsum = 0.0f, tsum = 0.0f, dsum = 0.0f;

    #pragma unroll
    for (int q = 0; q < 16; q++) {
        const float rwx = wx[q], rwy = wy[q];
        const float nrm = sqrtf(rwx * rwx + rwy * rwy);
        const float scl = 0.99f / (1.0f + nrm);
        const float wxx = scl * rwx, wyy = scl * rwy;
        const float wn2 = wxx * wxx + wyy * wyy;
        const float omw = 1.0f - wn2;
        // h_map(zv, w)
        const float dzx = cz - wxx, dzy = sz - wyy;
        const float dn2z = dzx * dzx + dzy * dzy;
        const float cf = omw / dn2z;
        const float hzx = cf * dzx - wxx;
        const float hzy = cf * dzy - wyy;
        // h_map((1,0), w)
        const float d0x = 1.0f - wxx, d0y = -wyy;
        const float dn20 = d0x * d0x + d0y * d0y;
        const float c0 = omw / dn20;
        const float h0x = c0 * d0x - wxx;
        const float h0y = c0 * d0y - wyy;
        // atan2(hz) - atan2(h0) == atan2(cross, dot)  (mod 2pi); both mapped
        // to [0, 2pi) afterwards -> identical to reference. |hz|=|h0|=1 so
        // (cross, dot) != (0,0).
        const float cross = hzy * h0x - hzx * h0y;
        const float dotp  = hzx * h0x + hzy * h0y;
        float tx = atan2f(cross, dotp);
        tx = (tx >= 0.0f) ? tx : tx + TWO_PI_F;

        const float ew = expf(th[q] - mx);
        wsum += ew;
        tsum += ew * tx;
        // |dh| = cf exactly (dh is cf * reflection of unit dz)
        dsum += ew * cf;
    }

    const float inv = 1.0f / wsum;
    const float tz  = tsum * inv;
    const float dtz = dsum * inv;
    const float ldj = logf(dtr) + logf(dtz);

    out[idx]         = tr;
    out[n + idx]     = tz;
    out[2 * n + idx] = ldj;
}

extern "C" void kernel_launch(void* const* d_in, const int* in_sizes, int n_in,
                              void* d_out, int out_size, void* d_ws, size_t ws_size,
                              hipStream_t stream) {
    const int n = in_sizes[0];  // 1,000,000
    float* ws = (float*)d_ws;

    // One-time table build (1 block), stream-ordered before the main kernel.
    hipLaunchKernelGGL(precompute_kernel, dim3(1), dim3(256), 0, stream,
                       (const float*)d_in[2], (const float*)d_in[3],
                       (const float*)d_in[4], (const float*)d_in[5],
                       (const float*)d_in[6], (const float*)d_in[7],
                       (const float*)d_in[8], ws);

    const int blocks = (n + 255) / 256;
    hipLaunchKernelGGL(mobius_spline_kernel, dim3(blocks), dim3(256), 0, stream,
                       (const float*)d_in[0], (const float*)d_in[1],
                       (const float*)d_in[9], (const float*)d_in[10],
                       (const float*)ws,
                       (float*)d_out, n);
}

// Round 5
// 179.252 us; speedup vs baseline: 4.9577x; 1.2574x over previous
//
#include <hip/hip_runtime.h>
#include <math.h>

#define KM 16
#define KS 64
#define TWO_PI_F 6.283185307179586477f

// Workspace float-offset layout (written by precompute_kernel, read by main):
//   [0..64]      sxk   (65)  spline x knots
//   [65..129]    syk   (65)  spline y knots
//   [130..194]   sdk   (65)  spline derivs
//   [195..258]   sknot (64)  sorted relu-toggle knots of phase-1 MLP
//   [259..4483]  A     (65*65, stride 65, col 64 unused)  h2_i = relu(A[v][i]*r + B[v][i])
//   [4484..8708] B     (65*65)
#define WS_SXK   0
#define WS_SYK   65
#define WS_SDK   130
#define WS_KNOT  195
#define WS_A     259
#define WS_B     (259 + 4225)

__device__ __forceinline__ float frcp(float x) { return __builtin_amdgcn_rcpf(x); }

// 4-quadrant atan2, polynomial on [0,1] after octant reduction.
// Max error ~1e-5 rad (tolerance is 3.1e-2 -> 3 orders of margin).
__device__ __forceinline__ float fast_atan2(float y, float x) {
    const float ax = fabsf(x), ay = fabsf(y);
    const float mx = fmaxf(ax, ay), mn = fminf(ax, ay);
    const float t = mn * frcp(mx);
    const float s = t * t;
    float p = -0.01172120f;
    p = fmaf(p, s,  0.05265332f);
    p = fmaf(p, s, -0.11643287f);
    p = fmaf(p, s,  0.19354346f);
    p = fmaf(p, s, -0.33262347f);
    p = fmaf(p, s,  0.99997726f);
    p = p * t;
    p = (ay > ax) ? (1.57079632679f - p) : p;
    p = (x < 0.0f) ? (3.14159265359f - p) : p;
    p = (y < 0.0f) ? -p : p;
    return p;
}

// ---------------------------------------------------------------------------
// Precompute: PARALLEL. 17 blocks x 256 threads, one (v,i) pair per thread.
// A_i(v), B_i(v) computed by DIRECT summation over j (no serial prefix):
//   active(j,v) = (W1_j>0 & rnk_j<v) | (W1_j<0 & rnk_j>=v);  W1_j==0 adds
//   relu(b1_j)*W2_ji to B unconditionally. Identical math to round-4's
//   prefix build (harness-verified), different summation order only.
// Block 0 additionally writes spline tables (shfl-scan cumsum) and knots.
// Round-4 version was 1 block of serial chains ~= 87 us; this is ~8 us.
// ---------------------------------------------------------------------------
__global__ __launch_bounds__(256)
void precompute_kernel(const float* __restrict__ theta_w,
                       const float* __restrict__ theta_h,
                       const float* __restrict__ theta_d,
                       const float* __restrict__ W1,
                       const float* __restrict__ b1,
                       const float* __restrict__ W2,
                       const float* __restrict__ b2,
                       float* __restrict__ ws)
{
    __shared__ float sW1[64], sb1[64], tjs[64];
    __shared__ int   srnk[64];
    __shared__ float sW2[64 * 64];

    const int tid = threadIdx.x;

    // stage W1, b1, knots tj
    if (tid < 64) {
        const float w1 = W1[tid];
        const float bb = b1[tid];
        sW1[tid] = w1;
        sb1[tid] = bb;
        tjs[tid] = (w1 != 0.0f) ? (-bb / w1) : INFINITY;
    }
    // stage W2 coalesced as float4
    {
        const float4* __restrict__ W2v = (const float4*)W2;
        float4* __restrict__ sW2v = (float4*)sW2;
        for (int t2 = tid; t2 < 1024; t2 += 256) sW2v[t2] = W2v[t2];
    }
    __syncthreads();

    // ranks (distinct, tie-break by index j)
    if (tid < 64) {
        const float t = tjs[tid];
        int rk = 0;
        #pragma unroll 1
        for (int k2 = 0; k2 < 64; k2++) {
            const float tk = tjs[k2];
            rk += (tk < t || (tk == t && k2 < tid)) ? 1 : 0;
        }
        srnk[tid] = rk;
    }
    __syncthreads();

    // ---- block 0: spline tables + sorted knot list ----
    if (blockIdx.x == 0 && tid < 64) {
        ws[WS_KNOT + srnk[tid]] = tjs[tid];   // permutation scatter

        float vw = theta_w[tid];
        float vh = theta_h[tid];
        float mw = vw, mh = vh;
        #pragma unroll
        for (int off = 32; off > 0; off >>= 1) {
            mw = fmaxf(mw, __shfl_xor(mw, off));
            mh = fmaxf(mh, __shfl_xor(mh, off));
        }
        const float ew = expf(vw - mw);
        const float eh = expf(vh - mh);
        float sumw = ew, sumh = eh;
        #pragma unroll
        for (int off = 32; off > 0; off >>= 1) {
            sumw += __shfl_xor(sumw, off);
            sumh += __shfl_xor(sumh, off);
        }
        float cw = ew / sumw * 2.0f;          // width_tid
        float ch = eh / sumh * 2.0f;          // height_tid
        // inclusive scan over 64 lanes (reassoc err ~1e-6, tol 3e-2)
        #pragma unroll
        for (int off = 1; off < 64; off <<= 1) {
            const float uw = __shfl_up(cw, off);
            const float uh = __shfl_up(ch, off);
            if (tid >= off) { cw += uw; ch += uh; }
        }
        ws[WS_SXK + 1 + tid] = cw - 1.0f;
        ws[WS_SYK + 1 + tid] = ch - 1.0f;
        if (tid < KS - 1) {
            const float x = theta_d[tid];
            const float sp = (x > 20.0f) ? x : log1pf(expf(x));
            ws[WS_SDK + 1 + tid] = sp + 0.001f;
        }
        if (tid == 0) {
            ws[WS_SXK] = -1.0f;
            ws[WS_SYK] = -1.0f;
            ws[WS_SDK] = 1.0f;
            ws[WS_SDK + KS] = 1.0f;
        }
    }

    // ---- A/B table: one (v,i) pair per thread ----
    const int p = blockIdx.x * 256 + tid;
    if (p < 65 * 64) {
        const int v = p >> 6;     // 0..64  (wave-uniform: 64 consecutive p share v)
        const int i = p & 63;
        float cA = 0.0f;
        float cB = b2[i];
        #pragma unroll 1
        for (int j = 0; j < 64; j++) {
            const float w1 = sW1[j];          // broadcast
            const float bb = sb1[j];
            const float w2 = sW2[j * 64 + i]; // stride-1 across lanes
            if (w1 > 0.0f) {
                if (srnk[j] < v)  { cA = fmaf(w1, w2, cA); cB = fmaf(bb, w2, cB); }
            } else if (w1 < 0.0f) {
                if (srnk[j] >= v) { cA = fmaf(w1, w2, cA); cB = fmaf(bb, w2, cB); }
            } else {
                cB = fmaf(fmaxf(bb, 0.0f), w2, cB);
            }
        }
        ws[WS_A + v * 65 + i] = cA;
        ws[WS_B + v * 65 + i] = cB;
    }
}

// ---------------------------------------------------------------------------
// Main per-point kernel: structure identical to round 4 (harness-verified);
// transcendentals/divides replaced with fast forms (err ~1e-5 << 3e-2 tol).
// ---------------------------------------------------------------------------
__global__ __launch_bounds__(256)
void mobius_spline_kernel(const float* __restrict__ r_in,
                          const float* __restrict__ z_in,
                          const float* __restrict__ W3,
                          const float* __restrict__ b3,
                          const float* __restrict__ ws,
                          float* __restrict__ out,
                          int n)
{
    __shared__ float sxk[KS + 1], syk[KS + 1], sdk[KS + 1];
    __shared__ float sknot[KS];
    __shared__ float sA[65 * 65], sB[65 * 65];   // stride 65 (odd) -> banks spread

    const int tid = threadIdx.x;

    for (int t2 = tid; t2 < 65; t2 += 256) {
        sxk[t2] = ws[WS_SXK + t2];
        syk[t2] = ws[WS_SYK + t2];
        sdk[t2] = ws[WS_SDK + t2];
    }
    for (int t2 = tid; t2 < 64; t2 += 256) sknot[t2] = ws[WS_KNOT + t2];
    for (int t2 = tid; t2 < 4225; t2 += 256) {
        sA[t2] = ws[WS_A + t2];
        sB[t2] = ws[WS_B + t2];
    }
    __syncthreads();

    const int idx = blockIdx.x * 256 + tid;
    if (idx >= n) return;

    const float rv = r_in[idx];
    const float zz = z_in[idx];

    // ---------------- spline ----------------
    int lo = 0, hi = KS + 1;
    while (lo < hi) {
        const int mid = (lo + hi) >> 1;
        if (sxk[mid] < rv) lo = mid + 1; else hi = mid;
    }
    int k = lo;
    k = (k == 0) ? 1 : k;
    k = (k == KS + 1) ? KS : k;
    k -= 1;
    const float x_k = sxk[k], x_nk = sxk[k + 1];
    const float y_k = syk[k], y_nk = syk[k + 1];
    const float d_k = sdk[k], d_nk = sdk[k + 1];
    const float rdx = frcp(x_nk - x_k);
    const float dy  = y_nk - y_k;
    const float s_k = dy * rdx;
    const float eps = (rv - x_k) * rdx;
    const float ome = 1.0f - eps;
    const float den = s_k + (d_nk + d_k - 2.0f * s_k) * eps * ome;
    const float rden = frcp(den);
    const float tr  = fmaf(dy * (s_k * eps * eps + d_k * eps * ome), rden, y_k);
    const float dtr = s_k * s_k * (d_nk * eps * eps + 2.0f * s_k * eps * ome + d_k * ome * ome)
                      * rden * rden;

    // ---------------- interval of r among MLP knots ----------------
    int lo2 = 0, hi2 = KS;               // itv in [0, 64]
    while (lo2 < hi2) {
        const int mid = (lo2 + hi2) >> 1;
        if (sknot[mid] < rv) lo2 = mid + 1; else hi2 = mid;
    }
    const int abase = lo2 * 65;

    // ---------------- fused phase 2: theta = h2 @ W3 + b3 ----------------
    float th[16], wx[16], wy[16];
    #pragma unroll
    for (int q = 0; q < 16; q++) {
        th[q] = b3[q];
        wx[q] = b3[16 + 2 * q];
        wy[q] = b3[17 + 2 * q];
    }

    #pragma unroll 4
    for (int i = 0; i < 64; i++) {
        const float hv = fmaxf(fmaf(rv, sA[abase + i], sB[abase + i]), 0.0f);
        const float* __restrict__ w3r = &W3[i * 48];   // contiguous row -> wide s_loads
        #pragma unroll
        for (int q = 0; q < 16; q++) {
            th[q] = fmaf(hv, w3r[q],          th[q]);
            wx[q] = fmaf(hv, w3r[16 + 2 * q], wx[q]);
            wy[q] = fmaf(hv, w3r[17 + 2 * q], wy[q]);
        }
    }

    // ---------------- softmax max ----------------
    float mx = th[0];
    #pragma unroll
    for (int q = 1; q < 16; q++) mx = fmaxf(mx, th[q]);

    float cz, sz;
    __sincosf(zz, &sz, &cz);

    float wsum = 0.0f, tsum = 0.0f, dsum = 0.0f;

    #pragma unroll
    for (int q = 0; q < 16; q++) {
        const float rwx = wx[q], rwy = wy[q];
        const float nrm = __builtin_amdgcn_sqrtf(rwx * rwx + rwy * rwy);
        const float scl = 0.99f * frcp(1.0f + nrm);
        const float wxx = scl * rwx, wyy = scl * rwy;
        const float wn2 = wxx * wxx + wyy * wyy;
        const float omw = 1.0f - wn2;
        // h_map(zv, w)
        const float dzx = cz - wxx, dzy = sz - wyy;
        const float dn2z = dzx * dzx + dzy * dzy;
        const float cf = omw * frcp(dn2z);
        const float hzx = cf * dzx - wxx;
        const float hzy = cf * dzy - wyy;
        // h_map((1,0), w)
        const float d0x = 1.0f - wxx, d0y = -wyy;
        const float dn20 = d0x * d0x + d0y * d0y;
        const float c0 = omw * frcp(dn20);
        const float h0x = c0 * d0x - wxx;
        const float h0y = c0 * d0y - wyy;
        // atan2(hz) - atan2(h0) == atan2(cross, dot) (mod 2pi)
        const float cross = hzy * h0x - hzx * h0y;
        const float dotp  = hzx * h0x + hzy * h0y;
        float tx = fast_atan2(cross, dotp);
        tx = (tx >= 0.0f) ? tx : tx + TWO_PI_F;

        const float ew = __expf(th[q] - mx);
        wsum += ew;
        tsum += ew * tx;
        // |dh| = cf exactly (dh is cf * reflection of unit dz)
        dsum += ew * cf;
    }

    const float inv = frcp(wsum);
    const float tz  = tsum * inv;
    const float dtz = dsum * inv;
    const float ldj = __logf(dtr) + __logf(dtz);

    out[idx]         = tr;
    out[n + idx]     = tz;
    out[2 * n + idx] = ldj;
}

extern "C" void kernel_launch(void* const* d_in, const int* in_sizes, int n_in,
                              void* d_out, int out_size, void* d_ws, size_t ws_size,
                              hipStream_t stream) {
    const int n = in_sizes[0];  // 1,000,000
    float* ws = (float*)d_ws;

    // Parallel one-time table build: 17 blocks cover 65*64 (v,i) pairs.
    hipLaunchKernelGGL(precompute_kernel, dim3(17), dim3(256), 0, stream,
                       (const float*)d_in[2], (const float*)d_in[3],
                       (const float*)d_in[4], (const float*)d_in[5],
                       (const float*)d_in[6], (const float*)d_in[7],
                       (const float*)d_in[8], ws);

    const int blocks = (n + 255) / 256;
    hipLaunchKernelGGL(mobius_spline_kernel, dim3(blocks), dim3(256), 0, stream,
                       (const float*)d_in[0], (const float*)d_in[1],
                       (const float*)d_in[9], (const float*)d_in[10],
                       (const float*)ws,
                       (float*)d_out, n);
}

// Round 6
// 167.398 us; speedup vs baseline: 5.3087x; 1.0708x over previous
//
#include <hip/hip_runtime.h>
#include <math.h>

#define KM 16
#define KS 64
#define TWO_PI_F 6.283185307179586477f

// Workspace float-offset layout:
//   [0..64]      sxk (65) spline x knots      [65..129]  syk (65)
//   [130..194]   sdk (65)                     [195..258] sknot (64) sorted outer knots
//   [259..4483]  A (65*65, fallback path)     [4484..8708] B (fallback path)
//   [8709..12868]  SROOT: 65 intervals * 64 sorted sub-roots
//   [12872..418471] COEF: 4225 regions * 96 floats (48 (a,b) pairs):
//                   theta_o(r) = a_o*r + b_o inside region (v,s)
#define WS_SXK   0
#define WS_SYK   65
#define WS_SDK   130
#define WS_KNOT  195
#define WS_A     259
#define WS_B     (259 + 4225)
#define WS_SROOT 8709
#define WS_COEF  12872
#define WS_NEED  (12872 + 4225 * 96)   // floats

__device__ __forceinline__ float frcp(float x) { return __builtin_amdgcn_rcpf(x); }

// 4-quadrant atan2, max err ~1e-5 rad (tolerance 3.1e-2).
__device__ __forceinline__ float fast_atan2(float y, float x) {
    const float ax = fabsf(x), ay = fabsf(y);
    const float mx = fmaxf(ax, ay), mn = fminf(ax, ay);
    const float t = mn * frcp(mx);
    const float s = t * t;
    float p = -0.01172120f;
    p = fmaf(p, s,  0.05265332f);
    p = fmaf(p, s, -0.11643287f);
    p = fmaf(p, s,  0.19354346f);
    p = fmaf(p, s, -0.33262347f);
    p = fmaf(p, s,  0.99997726f);
    p = p * t;
    p = (ay > ax) ? (1.57079632679f - p) : p;
    p = (x < 0.0f) ? (3.14159265359f - p) : p;
    p = (y < 0.0f) ? -p : p;
    return p;
}

// ---------------------------------------------------------------------------
// FAST-PATH precompute: 65 blocks, block v handles outer interval v.
// theta(r) is piecewise-linear: inside interval v, h2_i = relu(A_i r + B_i)
// toggles at root t*_i = -B_i/A_i. Sorted roots give 65 sub-regions; in each,
// theta_o(r) = a_o r + b_o with a_o = sum_{act} A_i W3_io,
// b_o = b3_o + sum_{act} B_i W3_io, act decided by sign at region midpoint.
// Block 0 additionally writes spline tables + sorted outer knots.
// ---------------------------------------------------------------------------
__global__ __launch_bounds__(256)
void precompute_full(const float* __restrict__ theta_w,
                     const float* __restrict__ theta_h,
                     const float* __restrict__ theta_d,
                     const float* __restrict__ W1,
                     const float* __restrict__ b1,
                     const float* __restrict__ W2,
                     const float* __restrict__ b2,
                     const float* __restrict__ W3,
                     const float* __restrict__ b3,
                     float* __restrict__ ws)
{
    __shared__ float sW1[64], sb1[64], tjs[64], sknotS[64];
    __shared__ int   srnk[64];
    __shared__ float sW2[64 * 64];
    __shared__ float sW3[64 * 48];
    __shared__ float sb3[48];
    __shared__ float sAv[64], sBv[64], rroot[64], rsort[64], rmid[65];

    const int tid = threadIdx.x;
    const int v = blockIdx.x;             // 0..64

    if (tid < 64) { sW1[tid] = W1[tid]; sb1[tid] = b1[tid]; }
    {
        const float4* __restrict__ a = (const float4*)W2;
        float4* b = (float4*)sW2;
        for (int t = tid; t < 1024; t += 256) b[t] = a[t];
    }
    {
        const float4* __restrict__ a = (const float4*)W3;
        float4* b = (float4*)sW3;
        for (int t = tid; t < 768; t += 256) b[t] = a[t];
    }
    if (tid < 48) sb3[tid] = b3[tid];
    __syncthreads();

    if (tid < 64)
        tjs[tid] = (sW1[tid] != 0.0f) ? (-sb1[tid] / sW1[tid]) : INFINITY;
    __syncthreads();
    if (tid < 64) {                       // distinct ranks, tie-break by index
        const float t = tjs[tid];
        int rk = 0;
        #pragma unroll 1
        for (int k2 = 0; k2 < 64; k2++) {
            const float tk = tjs[k2];
            rk += (tk < t || (tk == t && k2 < tid)) ? 1 : 0;
        }
        srnk[tid] = rk;
        sknotS[rk] = t;
    }
    __syncthreads();

    // ---- A,B for THIS interval v (same math as harness-verified R5) ----
    if (tid < 64) {
        const int i = tid;
        float cA = 0.0f, cB = b2[i];
        #pragma unroll 1
        for (int j = 0; j < 64; j++) {
            const float w1 = sW1[j];
            const float bb = sb1[j];
            const float w2 = sW2[j * 64 + i];
            if (w1 > 0.0f) {
                if (srnk[j] < v)  { cA = fmaf(w1, w2, cA); cB = fmaf(bb, w2, cB); }
            } else if (w1 < 0.0f) {
                if (srnk[j] >= v) { cA = fmaf(w1, w2, cA); cB = fmaf(bb, w2, cB); }
            } else {
                cB = fmaf(fmaxf(bb, 0.0f), w2, cB);
            }
        }
        sAv[i] = cA; sBv[i] = cB;
    }
    __syncthreads();

    // ---- sub-roots of this interval, sorted ----
    if (tid < 64)
        rroot[tid] = (sAv[tid] != 0.0f) ? (-sBv[tid] / sAv[tid]) : INFINITY;
    __syncthreads();
    if (tid < 64) {
        const float t = rroot[tid];
        int rk = 0;
        #pragma unroll 1
        for (int k2 = 0; k2 < 64; k2++) {
            const float tk = rroot[k2];
            rk += (tk < t || (tk == t && k2 < tid)) ? 1 : 0;
        }
        rsort[rk] = t;
        ws[WS_SROOT + v * 64 + rk] = t;
    }
    __syncthreads();

    // ---- region midpoints (clamped to outer interval; r in (-0.999,0.999)) ----
    const float x_lo = (v == 0)  ? -1.0f : sknotS[v - 1];
    const float x_hi = (v == 64) ?  1.0f : sknotS[v];
    if (tid < 65) {
        const int s = tid;
        const float lo = (s == 0)  ? x_lo : fmaxf(x_lo, rsort[s - 1]);
        const float hi = (s == 64) ? x_hi : fminf(x_hi, rsort[s]);
        rmid[s] = 0.5f * (lo + hi);   // empty regions -> unused rows, garbage OK
    }
    __syncthreads();

    // ---- coefficient rows: (s,o) pair per thread-iteration ----
    for (int p = tid; p < 65 * 48; p += 256) {
        const int s = p / 48;
        const int o = p - 48 * s;
        const float rm = rmid[s];
        float a = 0.0f, b = sb3[o];
        #pragma unroll 4
        for (int j = 0; j < 64; j++) {
            const float A = sAv[j], B = sBv[j];
            const float w3 = sW3[j * 48 + o];
            const float m = (fmaf(A, rm, B) > 0.0f) ? w3 : 0.0f;  // relu active?
            a = fmaf(A, m, a);
            b = fmaf(B, m, b);
        }
        float* __restrict__ row = ws + WS_COEF + (v * 65 + s) * 96;
        row[2 * o]     = a;
        row[2 * o + 1] = b;
    }

    // ---- block 0: spline tables + sorted outer knots ----
    if (v == 0 && tid < 64) {
        ws[WS_KNOT + tid] = sknotS[tid];

        float vw = theta_w[tid];
        float vh = theta_h[tid];
        float mw = vw, mh = vh;
        #pragma unroll
        for (int off = 32; off > 0; off >>= 1) {
            mw = fmaxf(mw, __shfl_xor(mw, off));
            mh = fmaxf(mh, __shfl_xor(mh, off));
        }
        const float ew = expf(vw - mw);
        const float eh = expf(vh - mh);
        float sumw = ew, sumh = eh;
        #pragma unroll
        for (int off = 32; off > 0; off >>= 1) {
            sumw += __shfl_xor(sumw, off);
            sumh += __shfl_xor(sumh, off);
        }
        float cw = ew / sumw * 2.0f;
        float ch = eh / sumh * 2.0f;
        #pragma unroll
        for (int off = 1; off < 64; off <<= 1) {   // inclusive shfl scan
            const float uw = __shfl_up(cw, off);
            const float uh = __shfl_up(ch, off);
            if (tid >= off) { cw += uw; ch += uh; }
        }
        ws[WS_SXK + 1 + tid] = cw - 1.0f;
        ws[WS_SYK + 1 + tid] = ch - 1.0f;
        if (tid < KS - 1) {
            const float x = theta_d[tid];
            const float sp = (x > 20.0f) ? x : log1pf(expf(x));
            ws[WS_SDK + 1 + tid] = sp + 0.001f;
        }
        if (tid == 0) {
            ws[WS_SXK] = -1.0f;
            ws[WS_SYK] = -1.0f;
            ws[WS_SDK] = 1.0f;
            ws[WS_SDK + KS] = 1.0f;
        }
    }
}

// ---------------------------------------------------------------------------
// FAST-PATH main kernel: spline + two binary searches + 24 float4 gathers
// + 48 FMA replace the 3072-FMA GEMM. Mobius/softmax unchanged (R5-verified).
// ---------------------------------------------------------------------------
__global__ __launch_bounds__(256)
void mobius_spline_kernel(const float* __restrict__ r_in,
                          const float* __restrict__ z_in,
                          const float* __restrict__ ws,
                          float* __restrict__ out,
                          int n)
{
    __shared__ float sxk[KS + 1], syk[KS + 1], sdk[KS + 1];
    __shared__ float sknot[KS];
    __shared__ float sroots[65 * 65];    // stride 65 (odd) -> banks spread

    const int tid = threadIdx.x;

    for (int t2 = tid; t2 < 65; t2 += 256) {
        sxk[t2] = ws[WS_SXK + t2];
        syk[t2] = ws[WS_SYK + t2];
        sdk[t2] = ws[WS_SDK + t2];
    }
    for (int t2 = tid; t2 < 64; t2 += 256) sknot[t2] = ws[WS_KNOT + t2];
    for (int t2 = tid; t2 < 65 * 64; t2 += 256) {
        const int v2 = t2 >> 6, m = t2 & 63;
        sroots[v2 * 65 + m] = ws[WS_SROOT + t2];
    }
    __syncthreads();

    const int idx = blockIdx.x * 256 + tid;
    if (idx >= n) return;

    const float rv = r_in[idx];
    const float zz = z_in[idx];

    // ---------------- spline ----------------
    int lo = 0, hi = KS + 1;
    while (lo < hi) {
        const int mid = (lo + hi) >> 1;
        if (sxk[mid] < rv) lo = mid + 1; else hi = mid;
    }
    int k = lo;
    k = (k == 0) ? 1 : k;
    k = (k == KS + 1) ? KS : k;
    k -= 1;
    const float x_k = sxk[k], x_nk = sxk[k + 1];
    const float y_k = syk[k], y_nk = syk[k + 1];
    const float d_k = sdk[k], d_nk = sdk[k + 1];
    const float rdx = frcp(x_nk - x_k);
    const float dy  = y_nk - y_k;
    const float s_k = dy * rdx;
    const float eps = (rv - x_k) * rdx;
    const float ome = 1.0f - eps;
    const float den = s_k + (d_nk + d_k - 2.0f * s_k) * eps * ome;
    const float rden = frcp(den);
    const float tr  = fmaf(dy * (s_k * eps * eps + d_k * eps * ome), rden, y_k);
    const float dtr = s_k * s_k * (d_nk * eps * eps + 2.0f * s_k * eps * ome + d_k * ome * ome)
                      * rden * rden;

    // ---------------- region lookup: outer interval v, sub-region s ----------
    int lo2 = 0, hi2 = KS;
    while (lo2 < hi2) {
        const int mid = (lo2 + hi2) >> 1;
        if (sknot[mid] < rv) lo2 = mid + 1; else hi2 = mid;
    }
    const int v = lo2;                    // 0..64
    const int rbase = v * 65;
    int lo3 = 0, hi3 = 64;
    while (lo3 < hi3) {
        const int mid = (lo3 + hi3) >> 1;
        if (sroots[rbase + mid] < rv) lo3 = mid + 1; else hi3 = mid;
    }
    const int s = lo3;                    // 0..64

    const float4* __restrict__ row4 =
        (const float4*)(ws + WS_COEF + (size_t)(v * 65 + s) * 96);

    // ---------------- theta logits: th_q = a*rv + b ----------------
    float th[16];
    #pragma unroll
    for (int o8 = 0; o8 < 8; o8++) {
        const float4 c = row4[o8];
        th[2 * o8]     = fmaf(c.x, rv, c.y);
        th[2 * o8 + 1] = fmaf(c.z, rv, c.w);
    }
    float mx = th[0];
    #pragma unroll
    for (int q = 1; q < 16; q++) mx = fmaxf(mx, th[q]);

    float cz, sz;
    __sincosf(zz, &sz, &cz);

    float wsum = 0.0f, tsum = 0.0f, dsum = 0.0f;

    #pragma unroll 4
    for (int q = 0; q < 16; q++) {
        const float4 c = row4[8 + q];     // (a_wx, b_wx, a_wy, b_wy)
        const float rwx = fmaf(c.x, rv, c.y);
        const float rwy = fmaf(c.z, rv, c.w);
        const float nrm = __builtin_amdgcn_sqrtf(rwx * rwx + rwy * rwy);
        const float scl = 0.99f * frcp(1.0f + nrm);
        const float wxx = scl * rwx, wyy = scl * rwy;
        const float wn2 = wxx * wxx + wyy * wyy;
        const float omw = 1.0f - wn2;
        const float dzx = cz - wxx, dzy = sz - wyy;
        const float dn2z = dzx * dzx + dzy * dzy;
        const float cf = omw * frcp(dn2z);
        const float hzx = cf * dzx - wxx;
        const float hzy = cf * dzy - wyy;
        const float d0x = 1.0f - wxx, d0y = -wyy;
        const float dn20 = d0x * d0x + d0y * d0y;
        const float c0 = omw * frcp(dn20);
        const float h0x = c0 * d0x - wxx;
        const float h0y = c0 * d0y - wyy;
        const float cross = hzy * h0x - hzx * h0y;
        const float dotp  = hzx * h0x + hzy * h0y;
        float tx = fast_atan2(cross, dotp);
        tx = (tx >= 0.0f) ? tx : tx + TWO_PI_F;

        const float ew = __expf(th[q] - mx);
        wsum += ew;
        tsum += ew * tx;
        dsum += ew * cf;                  // |dh| = cf exactly
    }

    const float inv = frcp(wsum);
    const float tz  = tsum * inv;
    const float dtz = dsum * inv;
    const float ldj = __logf(dtr) + __logf(dtz);

    out[idx]         = tr;
    out[n + idx]     = tz;
    out[2 * n + idx] = ldj;
}

// ---------------------------------------------------------------------------
// FALLBACK path (workspace too small for coeff table): round-5 kernels,
// harness-verified at 104 us main.
// ---------------------------------------------------------------------------
__global__ __launch_bounds__(256)
void precompute_fb(const float* __restrict__ theta_w,
                   const float* __restrict__ theta_h,
                   const float* __restrict__ theta_d,
                   const float* __restrict__ W1,
                   const float* __restrict__ b1,
                   const float* __restrict__ W2,
                   const float* __restrict__ b2,
                   float* __restrict__ ws)
{
    __shared__ float sW1[64], sb1[64], tjs[64];
    __shared__ int   srnk[64];
    __shared__ float sW2[64 * 64];

    const int tid = threadIdx.x;

    if (tid < 64) {
        const float w1 = W1[tid];
        const float bb = b1[tid];
        sW1[tid] = w1;
        sb1[tid] = bb;
        tjs[tid] = (w1 != 0.0f) ? (-bb / w1) : INFINITY;
    }
    {
        const float4* __restrict__ W2v = (const float4*)W2;
        float4* __restrict__ sW2v = (float4*)sW2;
        for (int t2 = tid; t2 < 1024; t2 += 256) sW2v[t2] = W2v[t2];
    }
    __syncthreads();

    if (tid < 64) {
        const float t = tjs[tid];
        int rk = 0;
        #pragma unroll 1
        for (int k2 = 0; k2 < 64; k2++) {
            const float tk = tjs[k2];
            rk += (tk < t || (tk == t && k2 < tid)) ? 1 : 0;
        }
        srnk[tid] = rk;
    }
    __syncthreads();

    if (blockIdx.x == 0 && tid < 64) {
        ws[WS_KNOT + srnk[tid]] = tjs[tid];
        float vw = theta_w[tid];
        float vh = theta_h[tid];
        float mw = vw, mh = vh;
        #pragma unroll
        for (int off = 32; off > 0; off >>= 1) {
            mw = fmaxf(mw, __shfl_xor(mw, off));
            mh = fmaxf(mh, __shfl_xor(mh, off));
        }
        const float ew = expf(vw - mw);
        const float eh = expf(vh - mh);
        float sumw = ew, sumh = eh;
        #pragma unroll
        for (int off = 32; off > 0; off >>= 1) {
            sumw += __shfl_xor(sumw, off);
            sumh += __shfl_xor(sumh, off);
        }
        float cw = ew / sumw * 2.0f;
        float ch = eh / sumh * 2.0f;
        #pragma unroll
        for (int off = 1; off < 64; off <<= 1) {
            const float uw = __shfl_up(cw, off);
            const float uh = __shfl_up(ch, off);
            if (tid >= off) { cw += uw; ch += uh; }
        }
        ws[WS_SXK + 1 + tid] = cw - 1.0f;
        ws[WS_SYK + 1 + tid] = ch - 1.0f;
        if (tid < KS - 1) {
            const float x = theta_d[tid];
            const float sp = (x > 20.0f) ? x : log1pf(expf(x));
            ws[WS_SDK + 1 + tid] = sp + 0.001f;
        }
        if (tid == 0) {
            ws[WS_SXK] = -1.0f;
            ws[WS_SYK] = -1.0f;
            ws[WS_SDK] = 1.0f;
            ws[WS_SDK + KS] = 1.0f;
        }
    }

    const int p = blockIdx.x * 256 + tid;
    if (p < 65 * 64) {
        const int v = p >> 6;
        const int i = p & 63;
        float cA = 0.0f;
        float cB = b2[i];
        #pragma unroll 1
        for (int j = 0; j < 64; j++) {
            const float w1 = sW1[j];
            const float bb = sb1[j];
            const float w2 = sW2[j * 64 + i];
            if (w1 > 0.0f) {
                if (srnk[j] < v)  { cA = fmaf(w1, w2, cA); cB = fmaf(bb, w2, cB); }
            } else if (w1 < 0.0f) {
                if (srnk[j] >= v) { cA = fmaf(w1, w2, cA); cB = fmaf(bb, w2, cB); }
            } else {
                cB = fmaf(fmaxf(bb, 0.0f), w2, cB);
            }
        }
        ws[WS_A + v * 65 + i] = cA;
        ws[WS_B + v * 65 + i] = cB;
    }
}

__global__ __launch_bounds__(256)
void mobius_spline_fb(const float* __restrict__ r_in,
                      const float* __restrict__ z_in,
                      const float* __restrict__ W3,
                      const float* __restrict__ b3,
                      const float* __restrict__ ws,
                      float* __restrict__ out,
                      int n)
{
    __shared__ float sxk[KS + 1], syk[KS + 1], sdk[KS + 1];
    __shared__ float sknot[KS];
    __shared__ float sA[65 * 65], sB[65 * 65];

    const int tid = threadIdx.x;

    for (int t2 = tid; t2 < 65; t2 += 256) {
        sxk[t2] = ws[WS_SXK + t2];
        syk[t2] = ws[WS_SYK + t2];
        sdk[t2] = ws[WS_SDK + t2];
    }
    for (int t2 = tid; t2 < 64; t2 += 256) sknot[t2] = ws[WS_KNOT + t2];
    for (int t2 = tid; t2 < 4225; t2 += 256) {
        sA[t2] = ws[WS_A + t2];
        sB[t2] = ws[WS_B + t2];
    }
    __syncthreads();

    const int idx = blockIdx.x * 256 + tid;
    if (idx >= n) return;

    const float rv = r_in[idx];
    const float zz = z_in[idx];

    int lo = 0, hi = KS + 1;
    while (lo < hi) {
        const int mid = (lo + hi) >> 1;
        if (sxk[mid] < rv) lo = mid + 1; else hi = mid;
    }
    int k = lo;
    k = (k == 0) ? 1 : k;
    k = (k == KS + 1) ? KS : k;
    k -= 1;
    const float x_k = sxk[k], x_nk = sxk[k + 1];
    const float y_k = syk[k], y_nk = syk[k + 1];
    const float d_k = sdk[k], d_nk = sdk[k + 1];
    const float rdx = frcp(x_nk - x_k);
    const float dy  = y_nk - y_k;
    const float s_k = dy * rdx;
    const float eps = (rv - x_k) * rdx;
    const float ome = 1.0f - eps;
    const float den = s_k + (d_nk + d_k - 2.0f * s_k) * eps * ome;
    const float rden = frcp(den);
    const float tr  = fmaf(dy * (s_k * eps * eps + d_k * eps * ome), rden, y_k);
    const float dtr = s_k * s_k * (d_nk * eps * eps + 2.0f * s_k * eps * ome + d_k * ome * ome)
                      * rden * rden;

    int lo2 = 0, hi2 = KS;
    while (lo2 < hi2) {
        const int mid = (lo2 + hi2) >> 1;
        if (sknot[mid] < rv) lo2 = mid + 1; else hi2 = mid;
    }
    const int abase = lo2 * 65;

    float th[16], wx[16], wy[16];
    #pragma unroll
    for (int q = 0; q < 16; q++) {
        th[q] = b3[q];
        wx[q] = b3[16 + 2 * q];
        wy[q] = b3[17 + 2 * q];
    }

    #pragma unroll 4
    for (int i = 0; i < 64; i++) {
        const float hv = fmaxf(fmaf(rv, sA[abase + i], sB[abase + i]), 0.0f);
        const float* __restrict__ w3r = &W3[i * 48];
        #pragma unroll
        for (int q = 0; q < 16; q++) {
            th[q] = fmaf(hv, w3r[q],          th[q]);
            wx[q] = fmaf(hv, w3r[16 + 2 * q], wx[q]);
            wy[q] = fmaf(hv, w3r[17 + 2 * q], wy[q]);
        }
    }

    float mx = th[0];
    #pragma unroll
    for (int q = 1; q < 16; q++) mx = fmaxf(mx, th[q]);

    float cz, sz;
    __sincosf(zz, &sz, &cz);

    float wsum = 0.0f, tsum = 0.0f, dsum = 0.0f;

    #pragma unroll
    for (int q = 0; q < 16; q++) {
        const float rwx = wx[q], rwy = wy[q];
        const float nrm = __builtin_amdgcn_sqrtf(rwx * rwx + rwy * rwy);
        const float scl = 0.99f * frcp(1.0f + nrm);
        const float wxx = scl * rwx, wyy = scl * rwy;
        const float wn2 = wxx * wxx + wyy * wyy;
        const float omw = 1.0f - wn2;
        const float dzx = cz - wxx, dzy = sz - wyy;
        const float dn2z = dzx * dzx + dzy * dzy;
        const float cf = omw * frcp(dn2z);
        const float hzx = cf * dzx - wxx;
        const float hzy = cf * dzy - wyy;
        const float d0x = 1.0f - wxx, d0y = -wyy;
        const float dn20 = d0x * d0x + d0y * d0y;
        const float c0 = omw * frcp(dn20);
        const float h0x = c0 * d0x - wxx;
        const float h0y = c0 * d0y - wyy;
        const float cross = hzy * h0x - hzx * h0y;
        const float dotp  = hzx * h0x + hzy * h0y;
        float tx = fast_atan2(cross, dotp);
        tx = (tx >= 0.0f) ? tx : tx + TWO_PI_F;

        const float ew = __expf(th[q] - mx);
        wsum += ew;
        tsum += ew * tx;
        dsum += ew * cf;
    }

    const float inv = frcp(wsum);
    const float tz  = tsum * inv;
    const float dtz = dsum * inv;
    const float ldj = __logf(dtr) + __logf(dtz);

    out[idx]         = tr;
    out[n + idx]     = tz;
    out[2 * n + idx] = ldj;
}

extern "C" void kernel_launch(void* const* d_in, const int* in_sizes, int n_in,
                              void* d_out, int out_size, void* d_ws, size_t ws_size,
                              hipStream_t stream) {
    const int n = in_sizes[0];  // 1,000,000
    float* ws = (float*)d_ws;
    const int blocks = (n + 255) / 256;

    if (ws_size >= (size_t)WS_NEED * sizeof(float)) {
        hipLaunchKernelGGL(precompute_full, dim3(65), dim3(256), 0, stream,
                           (const float*)d_in[2], (const float*)d_in[3],
                           (const float*)d_in[4], (const float*)d_in[5],
                           (const float*)d_in[6], (const float*)d_in[7],
                           (const float*)d_in[8], (const float*)d_in[9],
                           (const float*)d_in[10], ws);
        hipLaunchKernelGGL(mobius_spline_kernel, dim3(blocks), dim3(256), 0, stream,
                           (const float*)d_in[0], (const float*)d_in[1],
                           (const float*)ws, (float*)d_out, n);
    } else {
        hipLaunchKernelGGL(precompute_fb, dim3(17), dim3(256), 0, stream,
                           (const float*)d_in[2], (const float*)d_in[3],
                           (const float*)d_in[4], (const float*)d_in[5],
                           (const float*)d_in[6], (const float*)d_in[7],
                           (const float*)d_in[8], ws);
        hipLaunchKernelGGL(mobius_spline_fb, dim3(blocks), dim3(256), 0, stream,
                           (const float*)d_in[0], (const float*)d_in[1],
                           (const float*)d_in[9], (const float*)d_in[10],
                           (const float*)ws, (float*)d_out, n);
    }
}

// Round 7
// 152.496 us; speedup vs baseline: 5.8275x; 1.0977x over previous
//
#include <hip/hip_runtime.h>
#include <math.h>

#define KM 16
#define KS 64
#define TWO_PI_F 6.283185307179586477f

// Workspace float-offset layout:
//   [0..64]      sxk (65) spline x knots      [65..129]  syk (65)
//   [130..194]   sdk (65)                     [195..258] sknot (64) sorted outer knots
//   [259..4483]  A (65*65, fallback path)     [4484..8708] B (fallback path)
//   [8709..12868]  SROOT: 65 intervals * 64 sorted sub-roots
//   [12872..418471] COEF: 4225 regions * 96 floats (48 (a,b) pairs):
//                   theta_o(r) = a_o*r + b_o inside region (v,s)
#define WS_SXK   0
#define WS_SYK   65
#define WS_SDK   130
#define WS_KNOT  195
#define WS_A     259
#define WS_B     (259 + 4225)
#define WS_SROOT 8709
#define WS_COEF  12872
#define WS_NEED  (12872 + 4225 * 96)   // floats

__device__ __forceinline__ float frcp(float x) { return __builtin_amdgcn_rcpf(x); }

// 4-quadrant atan2, max err ~1e-5 rad (tolerance 3.1e-2).
__device__ __forceinline__ float fast_atan2(float y, float x) {
    const float ax = fabsf(x), ay = fabsf(y);
    const float mx = fmaxf(ax, ay), mn = fminf(ax, ay);
    const float t = mn * frcp(mx);
    const float s = t * t;
    float p = -0.01172120f;
    p = fmaf(p, s,  0.05265332f);
    p = fmaf(p, s, -0.11643287f);
    p = fmaf(p, s,  0.19354346f);
    p = fmaf(p, s, -0.33262347f);
    p = fmaf(p, s,  0.99997726f);
    p = p * t;
    p = (ay > ax) ? (1.57079632679f - p) : p;
    p = (x < 0.0f) ? (3.14159265359f - p) : p;
    p = (y < 0.0f) ? -p : p;
    return p;
}

// ---------------------------------------------------------------------------
// FAST-PATH precompute: 65 blocks, block v = outer interval v.
// R6 version spent ~50 us: coef loop did 3120 items x 64 j x 3 ds_read
// (~187K LDS reads/block, LDS-pipe-bound) and the rank loops were
// `unroll 1` serial dependent-LDS chains. This version:
//   - rank/AB loops unroll 8 (loads batch, one wait per group)
//   - coefficients built INCREMENTALLY along s: base sum (s=0) + one
//     toggle per s (the unit whose root has rank s-1). Exact set logic:
//     active_j(s) = (A_j>0 & rank_j<s) | (A_j<0 & rank_j>=s) | (A_j==0 & B_j>0).
//     Crossing unit contributes exactly 0 at the boundary (A*r+B=0), so
//     boundary handling is exact. ~400 ds_reads/block instead of 187K.
// ---------------------------------------------------------------------------
__global__ __launch_bounds__(256)
void precompute_full(const float* __restrict__ theta_w,
                     const float* __restrict__ theta_h,
                     const float* __restrict__ theta_d,
                     const float* __restrict__ W1,
                     const float* __restrict__ b1,
                     const float* __restrict__ W2,
                     const float* __restrict__ b2,
                     const float* __restrict__ W3,
                     const float* __restrict__ b3,
                     float* __restrict__ ws)
{
    __shared__ float sW1[64], sb1[64], tjs[64], sknotS[64];
    __shared__ int   srnk[64];
    __shared__ float sW2[64 * 64];
    __shared__ float sW3[64 * 48];
    __shared__ float sb3[48];
    __shared__ float sAv[64], sBv[64], rroot[64];
    __shared__ int   jinv[64];

    const int tid = threadIdx.x;
    const int v = blockIdx.x;             // 0..64

    if (tid < 64) { sW1[tid] = W1[tid]; sb1[tid] = b1[tid]; }
    {
        const float4* __restrict__ a = (const float4*)W2;
        float4* b = (float4*)sW2;
        for (int t = tid; t < 1024; t += 256) b[t] = a[t];
    }
    {
        const float4* __restrict__ a = (const float4*)W3;
        float4* b = (float4*)sW3;
        for (int t = tid; t < 768; t += 256) b[t] = a[t];
    }
    if (tid < 48) sb3[tid] = b3[tid];
    __syncthreads();

    if (tid < 64)
        tjs[tid] = (sW1[tid] != 0.0f) ? (-sb1[tid] / sW1[tid]) : INFINITY;
    __syncthreads();
    if (tid < 64) {                       // distinct ranks, tie-break by index
        const float t = tjs[tid];
        int rk = 0;
        #pragma unroll 8
        for (int k2 = 0; k2 < 64; k2++) {
            const float tk = tjs[k2];
            rk += (tk < t || (tk == t && k2 < tid)) ? 1 : 0;
        }
        srnk[tid] = rk;
        sknotS[rk] = t;
    }
    __syncthreads();

    // ---- A,B for THIS interval v (same math as harness-verified R5/R6) ----
    if (tid < 64) {
        const int i = tid;
        float cA = 0.0f, cB = b2[i];
        #pragma unroll 8
        for (int j = 0; j < 64; j++) {
            const float w1 = sW1[j];
            const float bb = sb1[j];
            const float w2 = sW2[j * 64 + i];
            if (w1 > 0.0f) {
                if (srnk[j] < v)  { cA = fmaf(w1, w2, cA); cB = fmaf(bb, w2, cB); }
            } else if (w1 < 0.0f) {
                if (srnk[j] >= v) { cA = fmaf(w1, w2, cA); cB = fmaf(bb, w2, cB); }
            } else {
                cB = fmaf(fmaxf(bb, 0.0f), w2, cB);
            }
        }
        sAv[i] = cA; sBv[i] = cB;
    }
    __syncthreads();

    // ---- sub-roots of this interval, ranks, inverse-rank, sorted write ----
    if (tid < 64)
        rroot[tid] = (sAv[tid] != 0.0f) ? (-sBv[tid] / sAv[tid]) : INFINITY;
    __syncthreads();
    if (tid < 64) {
        const float t = rroot[tid];
        int rk = 0;
        #pragma unroll 8
        for (int k2 = 0; k2 < 64; k2++) {
            const float tk = rroot[k2];
            rk += (tk < t || (tk == t && k2 < tid)) ? 1 : 0;
        }
        jinv[rk] = tid;                      // inverse permutation
        ws[WS_SROOT + v * 64 + rk] = t;      // sorted roots for main kernel
    }
    __syncthreads();

    // ---- coefficient rows, incremental along s. One wave, lane = o ----
    if (tid < 48) {
        const int o = tid;
        // base s=0: active = (A<0) | (A==0 & B>0)
        float a = 0.0f, b = sb3[o];
        #pragma unroll 8
        for (int j = 0; j < 64; j++) {
            const float A = sAv[j], B = sBv[j];
            const float w3 = sW3[j * 48 + o];
            const bool act = (A < 0.0f) || (A == 0.0f && B > 0.0f);
            const float m = act ? w3 : 0.0f;
            a = fmaf(A, m, a);
            b = fmaf(B, m, b);
        }
        float* __restrict__ rowbase = ws + WS_COEF + (size_t)(v * 65) * 96;
        rowbase[2 * o]     = a;
        rowbase[2 * o + 1] = b;
        #pragma unroll 4
        for (int s = 1; s <= 64; s++) {
            const int js = jinv[s - 1];      // the unit whose root is crossed
            const float A = sAv[js], B = sBv[js];
            const float w3 = sW3[js * 48 + o];
            // A>0: turns ON (+); A<0: turns OFF (-); A==0: no root, no toggle
            const float sgn = (A > 0.0f) ? w3 : ((A < 0.0f) ? -w3 : 0.0f);
            a = fmaf(A, sgn, a);
            b = fmaf(B, sgn, b);
            rowbase[s * 96 + 2 * o]     = a;
            rowbase[s * 96 + 2 * o + 1] = b;
        }
    }

    // ---- block 0: spline tables + sorted outer knots ----
    if (v == 0 && tid < 64) {
        ws[WS_KNOT + tid] = sknotS[tid];

        float vw = theta_w[tid];
        float vh = theta_h[tid];
        float mw = vw, mh = vh;
        #pragma unroll
        for (int off = 32; off > 0; off >>= 1) {
            mw = fmaxf(mw, __shfl_xor(mw, off));
            mh = fmaxf(mh, __shfl_xor(mh, off));
        }
        const float ew = expf(vw - mw);
        const float eh = expf(vh - mh);
        float sumw = ew, sumh = eh;
        #pragma unroll
        for (int off = 32; off > 0; off >>= 1) {
            sumw += __shfl_xor(sumw, off);
            sumh += __shfl_xor(sumh, off);
        }
        float cw = ew / sumw * 2.0f;
        float ch = eh / sumh * 2.0f;
        #pragma unroll
        for (int off = 1; off < 64; off <<= 1) {   // inclusive shfl scan
            const float uw = __shfl_up(cw, off);
            const float uh = __shfl_up(ch, off);
            if (tid >= off) { cw += uw; ch += uh; }
        }
        ws[WS_SXK + 1 + tid] = cw - 1.0f;
        ws[WS_SYK + 1 + tid] = ch - 1.0f;
        if (tid < KS - 1) {
            const float x = theta_d[tid];
            const float sp = (x > 20.0f) ? x : log1pf(expf(x));
            ws[WS_SDK + 1 + tid] = sp + 0.001f;
        }
        if (tid == 0) {
            ws[WS_SXK] = -1.0f;
            ws[WS_SYK] = -1.0f;
            ws[WS_SDK] = 1.0f;
            ws[WS_SDK + KS] = 1.0f;
        }
    }
}

// ---------------------------------------------------------------------------
// FAST-PATH main kernel (R6-verified structure, 59.5 us): spline + two
// binary searches + 24 float4 gathers + 48 FMA. Only change: q-loop fully
// unrolled so all 16 row4 gathers issue early (VGPR headroom: was 32).
// ---------------------------------------------------------------------------
__global__ __launch_bounds__(256)
void mobius_spline_kernel(const float* __restrict__ r_in,
                          const float* __restrict__ z_in,
                          const float* __restrict__ ws,
                          float* __restrict__ out,
                          int n)
{
    __shared__ float sxk[KS + 1], syk[KS + 1], sdk[KS + 1];
    __shared__ float sknot[KS];
    __shared__ float sroots[65 * 65];    // stride 65 (odd) -> banks spread

    const int tid = threadIdx.x;

    for (int t2 = tid; t2 < 65; t2 += 256) {
        sxk[t2] = ws[WS_SXK + t2];
        syk[t2] = ws[WS_SYK + t2];
        sdk[t2] = ws[WS_SDK + t2];
    }
    for (int t2 = tid; t2 < 64; t2 += 256) sknot[t2] = ws[WS_KNOT + t2];
    for (int t2 = tid; t2 < 65 * 64; t2 += 256) {
        const int v2 = t2 >> 6, m = t2 & 63;
        sroots[v2 * 65 + m] = ws[WS_SROOT + t2];
    }
    __syncthreads();

    const int idx = blockIdx.x * 256 + tid;
    if (idx >= n) return;

    const float rv = r_in[idx];
    const float zz = z_in[idx];

    // ---------------- spline ----------------
    int lo = 0, hi = KS + 1;
    while (lo < hi) {
        const int mid = (lo + hi) >> 1;
        if (sxk[mid] < rv) lo = mid + 1; else hi = mid;
    }
    int k = lo;
    k = (k == 0) ? 1 : k;
    k = (k == KS + 1) ? KS : k;
    k -= 1;
    const float x_k = sxk[k], x_nk = sxk[k + 1];
    const float y_k = syk[k], y_nk = syk[k + 1];
    const float d_k = sdk[k], d_nk = sdk[k + 1];
    const float rdx = frcp(x_nk - x_k);
    const float dy  = y_nk - y_k;
    const float s_k = dy * rdx;
    const float eps = (rv - x_k) * rdx;
    const float ome = 1.0f - eps;
    const float den = s_k + (d_nk + d_k - 2.0f * s_k) * eps * ome;
    const float rden = frcp(den);
    const float tr  = fmaf(dy * (s_k * eps * eps + d_k * eps * ome), rden, y_k);
    const float dtr = s_k * s_k * (d_nk * eps * eps + 2.0f * s_k * eps * ome + d_k * ome * ome)
                      * rden * rden;

    // ---------------- region lookup: outer interval v, sub-region s ----------
    int lo2 = 0, hi2 = KS;
    while (lo2 < hi2) {
        const int mid = (lo2 + hi2) >> 1;
        if (sknot[mid] < rv) lo2 = mid + 1; else hi2 = mid;
    }
    const int v = lo2;                    // 0..64
    const int rbase = v * 65;
    int lo3 = 0, hi3 = 64;
    while (lo3 < hi3) {
        const int mid = (lo3 + hi3) >> 1;
        if (sroots[rbase + mid] < rv) lo3 = mid + 1; else hi3 = mid;
    }
    const int s = lo3;                    // 0..64

    const float4* __restrict__ row4 =
        (const float4*)(ws + WS_COEF + (size_t)(v * 65 + s) * 96);

    // ---------------- theta logits: th_q = a*rv + b ----------------
    float th[16];
    #pragma unroll
    for (int o8 = 0; o8 < 8; o8++) {
        const float4 c = row4[o8];
        th[2 * o8]     = fmaf(c.x, rv, c.y);
        th[2 * o8 + 1] = fmaf(c.z, rv, c.w);
    }
    float mx = th[0];
    #pragma unroll
    for (int q = 1; q < 16; q++) mx = fmaxf(mx, th[q]);

    float cz, sz;
    __sincosf(zz, &sz, &cz);

    float wsum = 0.0f, tsum = 0.0f, dsum = 0.0f;

    #pragma unroll
    for (int q = 0; q < 16; q++) {
        const float4 c = row4[8 + q];     // (a_wx, b_wx, a_wy, b_wy)
        const float rwx = fmaf(c.x, rv, c.y);
        const float rwy = fmaf(c.z, rv, c.w);
        const float nrm = __builtin_amdgcn_sqrtf(rwx * rwx + rwy * rwy);
        const float scl = 0.99f * frcp(1.0f + nrm);
        const float wxx = scl * rwx, wyy = scl * rwy;
        const float wn2 = wxx * wxx + wyy * wyy;
        const float omw = 1.0f - wn2;
        const float dzx = cz - wxx, dzy = sz - wyy;
        const float dn2z = dzx * dzx + dzy * dzy;
        const float cf = omw * frcp(dn2z);
        const float hzx = cf * dzx - wxx;
        const float hzy = cf * dzy - wyy;
        const float d0x = 1.0f - wxx, d0y = -wyy;
        const float dn20 = d0x * d0x + d0y * d0y;
        const float c0 = omw * frcp(dn20);
        const float h0x = c0 * d0x - wxx;
        const float h0y = c0 * d0y - wyy;
        const float cross = hzy * h0x - hzx * h0y;
        const float dotp  = hzx * h0x + hzy * h0y;
        float tx = fast_atan2(cross, dotp);
        tx = (tx >= 0.0f) ? tx : tx + TWO_PI_F;

        const float ew = __expf(th[q] - mx);
        wsum += ew;
        tsum += ew * tx;
        dsum += ew * cf;                  // |dh| = cf exactly
    }

    const float inv = frcp(wsum);
    const float tz  = tsum * inv;
    const float dtz = dsum * inv;
    const float ldj = __logf(dtr) + __logf(dtz);

    out[idx]         = tr;
    out[n + idx]     = tz;
    out[2 * n + idx] = ldj;
}

// ---------------------------------------------------------------------------
// FALLBACK path (workspace too small for coeff table): round-5 kernels,
// harness-verified at 104 us main.
// ---------------------------------------------------------------------------
__global__ __launch_bounds__(256)
void precompute_fb(const float* __restrict__ theta_w,
                   const float* __restrict__ theta_h,
                   const float* __restrict__ theta_d,
                   const float* __restrict__ W1,
                   const float* __restrict__ b1,
                   const float* __restrict__ W2,
                   const float* __restrict__ b2,
                   float* __restrict__ ws)
{
    __shared__ float sW1[64], sb1[64], tjs[64];
    __shared__ int   srnk[64];
    __shared__ float sW2[64 * 64];

    const int tid = threadIdx.x;

    if (tid < 64) {
        const float w1 = W1[tid];
        const float bb = b1[tid];
        sW1[tid] = w1;
        sb1[tid] = bb;
        tjs[tid] = (w1 != 0.0f) ? (-bb / w1) : INFINITY;
    }
    {
        const float4* __restrict__ W2v = (const float4*)W2;
        float4* __restrict__ sW2v = (float4*)sW2;
        for (int t2 = tid; t2 < 1024; t2 += 256) sW2v[t2] = W2v[t2];
    }
    __syncthreads();

    if (tid < 64) {
        const float t = tjs[tid];
        int rk = 0;
        #pragma unroll 8
        for (int k2 = 0; k2 < 64; k2++) {
            const float tk = tjs[k2];
            rk += (tk < t || (tk == t && k2 < tid)) ? 1 : 0;
        }
        srnk[tid] = rk;
    }
    __syncthreads();

    if (blockIdx.x == 0 && tid < 64) {
        ws[WS_KNOT + srnk[tid]] = tjs[tid];
        float vw = theta_w[tid];
        float vh = theta_h[tid];
        float mw = vw, mh = vh;
        #pragma unroll
        for (int off = 32; off > 0; off >>= 1) {
            mw = fmaxf(mw, __shfl_xor(mw, off));
            mh = fmaxf(mh, __shfl_xor(mh, off));
        }
        const float ew = expf(vw - mw);
        const float eh = expf(vh - mh);
        float sumw = ew, sumh = eh;
        #pragma unroll
        for (int off = 32; off > 0; off >>= 1) {
            sumw += __shfl_xor(sumw, off);
            sumh += __shfl_xor(sumh, off);
        }
        float cw = ew / sumw * 2.0f;
        float ch = eh / sumh * 2.0f;
        #pragma unroll
        for (int off = 1; off < 64; off <<= 1) {
            const float uw = __shfl_up(cw, off);
            const float uh = __shfl_up(ch, off);
            if (tid >= off) { cw += uw; ch += uh; }
        }
        ws[WS_SXK + 1 + tid] = cw - 1.0f;
        ws[WS_SYK + 1 + tid] = ch - 1.0f;
        if (tid < KS - 1) {
            const float x = theta_d[tid];
            const float sp = (x > 20.0f) ? x : log1pf(expf(x));
            ws[WS_SDK + 1 + tid] = sp + 0.001f;
        }
        if (tid == 0) {
            ws[WS_SXK] = -1.0f;
            ws[WS_SYK] = -1.0f;
            ws[WS_SDK] = 1.0f;
            ws[WS_SDK + KS] = 1.0f;
        }
    }

    const int p = blockIdx.x * 256 + tid;
    if (p < 65 * 64) {
        const int v = p >> 6;
        const int i = p & 63;
        float cA = 0.0f;
        float cB = b2[i];
        #pragma unroll 1
        for (int j = 0; j < 64; j++) {
            const float w1 = sW1[j];
            const float bb = sb1[j];
            const float w2 = sW2[j * 64 + i];
            if (w1 > 0.0f) {
                if (srnk[j] < v)  { cA = fmaf(w1, w2, cA); cB = fmaf(bb, w2, cB); }
            } else if (w1 < 0.0f) {
                if (srnk[j] >= v) { cA = fmaf(w1, w2, cA); cB = fmaf(bb, w2, cB); }
            } else {
                cB = fmaf(fmaxf(bb, 0.0f), w2, cB);
            }
        }
        ws[WS_A + v * 65 + i] = cA;
        ws[WS_B + v * 65 + i] = cB;
    }
}

__global__ __launch_bounds__(256)
void mobius_spline_fb(const float* __restrict__ r_in,
                      const float* __restrict__ z_in,
                      const float* __restrict__ W3,
                      const float* __restrict__ b3,
                      const float* __restrict__ ws,
                      float* __restrict__ out,
                      int n)
{
    __shared__ float sxk[KS + 1], syk[KS + 1], sdk[KS + 1];
    __shared__ float sknot[KS];
    __shared__ float sA[65 * 65], sB[65 * 65];

    const int tid = threadIdx.x;

    for (int t2 = tid; t2 < 65; t2 += 256) {
        sxk[t2] = ws[WS_SXK + t2];
        syk[t2] = ws[WS_SYK + t2];
        sdk[t2] = ws[WS_SDK + t2];
    }
    for (int t2 = tid; t2 < 64; t2 += 256) sknot[t2] = ws[WS_KNOT + t2];
    for (int t2 = tid; t2 < 4225; t2 += 256) {
        sA[t2] = ws[WS_A + t2];
        sB[t2] = ws[WS_B + t2];
    }
    __syncthreads();

    const int idx = blockIdx.x * 256 + tid;
    if (idx >= n) return;

    const float rv = r_in[idx];
    const float zz = z_in[idx];

    int lo = 0, hi = KS + 1;
    while (lo < hi) {
        const int mid = (lo + hi) >> 1;
        if (sxk[mid] < rv) lo = mid + 1; else hi = mid;
    }
    int k = lo;
    k = (k == 0) ? 1 : k;
    k = (k == KS + 1) ? KS : k;
    k -= 1;
    const float x_k = sxk[k], x_nk = sxk[k + 1];
    const float y_k = syk[k], y_nk = syk[k + 1];
    const float d_k = sdk[k], d_nk = sdk[k + 1];
    const float rdx = frcp(x_nk - x_k);
    const float dy  = y_nk - y_k;
    const float s_k = dy * rdx;
    const float eps = (rv - x_k) * rdx;
    const float ome = 1.0f - eps;
    const float den = s_k + (d_nk + d_k - 2.0f * s_k) * eps * ome;
    const float rden = frcp(den);
    const float tr  = fmaf(dy * (s_k * eps * eps + d_k * eps * ome), rden, y_k);
    const float dtr = s_k * s_k * (d_nk * eps * eps + 2.0f * s_k * eps * ome + d_k * ome * ome)
                      * rden * rden;

    int lo2 = 0, hi2 = KS;
    while (lo2 < hi2) {
        const int mid = (lo2 + hi2) >> 1;
        if (sknot[mid] < rv) lo2 = mid + 1; else hi2 = mid;
    }
    const int abase = lo2 * 65;

    float th[16], wx[16], wy[16];
    #pragma unroll
    for (int q = 0; q < 16; q++) {
        th[q] = b3[q];
        wx[q] = b3[16 + 2 * q];
        wy[q] = b3[17 + 2 * q];
    }

    #pragma unroll 4
    for (int i = 0; i < 64; i++) {
        const float hv = fmaxf(fmaf(rv, sA[abase + i], sB[abase + i]), 0.0f);
        const float* __restrict__ w3r = &W3[i * 48];
        #pragma unroll
        for (int q = 0; q < 16; q++) {
            th[q] = fmaf(hv, w3r[q],          th[q]);
            wx[q] = fmaf(hv, w3r[16 + 2 * q], wx[q]);
            wy[q] = fmaf(hv, w3r[17 + 2 * q], wy[q]);
        }
    }

    float mx = th[0];
    #pragma unroll
    for (int q = 1; q < 16; q++) mx = fmaxf(mx, th[q]);

    float cz, sz;
    __sincosf(zz, &sz, &cz);

    float wsum = 0.0f, tsum = 0.0f, dsum = 0.0f;

    #pragma unroll
    for (int q = 0; q < 16; q++) {
        const float rwx = wx[q], rwy = wy[q];
        const float nrm = __builtin_amdgcn_sqrtf(rwx * rwx + rwy * rwy);
        const float scl = 0.99f * frcp(1.0f + nrm);
        const float wxx = scl * rwx, wyy = scl * rwy;
        const float wn2 = wxx * wxx + wyy * wyy;
        const float omw = 1.0f - wn2;
        const float dzx = cz - wxx, dzy = sz - wyy;
        const float dn2z = dzx * dzx + dzy * dzy;
        const float cf = omw * frcp(dn2z);
        const float hzx = cf * dzx - wxx;
        const float hzy = cf * dzy - wyy;
        const float d0x = 1.0f - wxx, d0y = -wyy;
        const float dn20 = d0x * d0x + d0y * d0y;
        const float c0 = omw * frcp(dn20);
        const float h0x = c0 * d0x - wxx;
        const float h0y = c0 * d0y - wyy;
        const float cross = hzy * h0x - hzx * h0y;
        const float dotp  = hzx * h0x + hzy * h0y;
        float tx = fast_atan2(cross, dotp);
        tx = (tx >= 0.0f) ? tx : tx + TWO_PI_F;

        const float ew = __expf(th[q] - mx);
        wsum += ew;
        tsum += ew * tx;
        dsum += ew * cf;
    }

    const float inv = frcp(wsum);
    const float tz  = tsum * inv;
    const float dtz = dsum * inv;
    const float ldj = __logf(dtr) + __logf(dtz);

    out[idx]         = tr;
    out[n + idx]     = tz;
    out[2 * n + idx] = ldj;
}

extern "C" void kernel_launch(void* const* d_in, const int* in_sizes, int n_in,
                              void* d_out, int out_size, void* d_ws, size_t ws_size,
                              hipStream_t stream) {
    const int n = in_sizes[0];  // 1,000,000
    float* ws = (float*)d_ws;
    const int blocks = (n + 255) / 256;

    if (ws_size >= (size_t)WS_NEED * sizeof(float)) {
        hipLaunchKernelGGL(precompute_full, dim3(65), dim3(256), 0, stream,
                           (const float*)d_in[2], (const float*)d_in[3],
                           (const float*)d_in[4], (const float*)d_in[5],
                           (const float*)d_in[6], (const float*)d_in[7],
                           (const float*)d_in[8], (const float*)d_in[9],
                           (const float*)d_in[10], ws);
        hipLaunchKernelGGL(mobius_spline_kernel, dim3(blocks), dim3(256), 0, stream,
                           (const float*)d_in[0], (const float*)d_in[1],
                           (const float*)ws, (float*)d_out, n);
    } else {
        hipLaunchKernelGGL(precompute_fb, dim3(17), dim3(256), 0, stream,
                           (const float*)d_in[2], (const float*)d_in[3],
                           (const float*)d_in[4], (const float*)d_in[5],
                           (const float*)d_in[6], (const float*)d_in[7],
                           (const float*)d_in[8], ws);
        hipLaunchKernelGGL(mobius_spline_fb, dim3(blocks), dim3(256), 0, stream,
                           (const float*)d_in[0], (const float*)d_in[1],
                           (const float*)d_in[9], (const float*)d_in[10],
                           (const float*)ws, (float*)d_out, n);
    }
}

// Round 8
// 150.343 us; speedup vs baseline: 5.9110x; 1.0143x over previous
//
#include <hip/hip_runtime.h>
#include <math.h>

#define KM 16
#define KS 64
#define TWO_PI_F 6.283185307179586477f

// Workspace float-offset layout:
//   [0..64]      sxk (65) spline x knots      [65..129]  syk (65)
//   [130..194]   sdk (65)                     [195..258] sknot (64) sorted outer knots
//   [259..4483]  A (65*65, fallback path)     [4484..8708] B (fallback path)
//   [8709..12868]  SROOT: 65 intervals * 64 sorted sub-roots
//   [12872..418471] COEF: 4225 regions * 96 floats (48 (a,b) pairs):
//                   theta_o(r) = a_o*r + b_o inside region (v,s)
#define WS_SXK   0
#define WS_SYK   65
#define WS_SDK   130
#define WS_KNOT  195
#define WS_A     259
#define WS_B     (259 + 4225)
#define WS_SROOT 8709
#define WS_COEF  12872
#define WS_NEED  (12872 + 4225 * 96)   // floats

__device__ __forceinline__ float frcp(float x) { return __builtin_amdgcn_rcpf(x); }

// 4-quadrant atan2, max err ~1e-5 rad (tolerance 3.1e-2).
__device__ __forceinline__ float fast_atan2(float y, float x) {
    const float ax = fabsf(x), ay = fabsf(y);
    const float mx = fmaxf(ax, ay), mn = fminf(ax, ay);
    const float t = mn * frcp(mx);
    const float s = t * t;
    float p = -0.01172120f;
    p = fmaf(p, s,  0.05265332f);
    p = fmaf(p, s, -0.11643287f);
    p = fmaf(p, s,  0.19354346f);
    p = fmaf(p, s, -0.33262347f);
    p = fmaf(p, s,  0.99997726f);
    p = p * t;
    p = (ay > ax) ? (1.57079632679f - p) : p;
    p = (x < 0.0f) ? (3.14159265359f - p) : p;
    p = (y < 0.0f) ? -p : p;
    return p;
}

// ---------------------------------------------------------------------------
// FAST-PATH precompute: 65 blocks, block v = outer interval v.
// R7 took ~49 us: the coefficient s-loop was 64 SERIAL iterations of a
// two-deep dependent LDS chain run by one wave, and sW3[j*48+o] reads were a
// 32-way bank conflict (bank = (16j+o)%32). This version:
//   - coefficient rows via wave-parallel PREFIX SUM: lane l computes the
//     toggle delta of sub-region s=l+1 (unit jinv[l]); 6-step shfl_up
//     inclusive scan + 6-step shfl_xor base reduce give all 65 rows of a
//     column at once. No serial chains (shfl is in-register).
//   - 4 waves x 12 columns; per-lane invariants hoisted out of the o-loop.
//   - sW3 padded to stride 49 -> bank (17j+o)%32, conflict-free.
// Same math as the harness-verified R7 (different summation order only).
// ---------------------------------------------------------------------------
__global__ __launch_bounds__(256)
void precompute_full(const float* __restrict__ theta_w,
                     const float* __restrict__ theta_h,
                     const float* __restrict__ theta_d,
                     const float* __restrict__ W1,
                     const float* __restrict__ b1,
                     const float* __restrict__ W2,
                     const float* __restrict__ b2,
                     const float* __restrict__ W3,
                     const float* __restrict__ b3,
                     float* __restrict__ ws)
{
    __shared__ float sW1[64], sb1[64], tjs[64], sknotS[64];
    __shared__ int   srnk[64];
    __shared__ float sW2[64 * 64];
    __shared__ float sW3[64 * 49];       // stride 49: conflict-free scattered reads
    __shared__ float sAv[64], sBv[64], rroot[64];
    __shared__ int   jinv[64];

    const int tid  = threadIdx.x;
    const int lane = tid & 63;
    const int wv   = tid >> 6;
    const int v = blockIdx.x;             // 0..64

    if (tid < 64) { sW1[tid] = W1[tid]; sb1[tid] = b1[tid]; }
    {
        const float4* __restrict__ a = (const float4*)W2;
        float4* b = (float4*)sW2;
        for (int t = tid; t < 1024; t += 256) b[t] = a[t];
    }
    for (int t = tid; t < 3072; t += 256)            // W3 with stride-49 pad
        sW3[(t / 48) * 49 + (t % 48)] = W3[t];
    __syncthreads();

    if (tid < 64)
        tjs[tid] = (sW1[tid] != 0.0f) ? (-sb1[tid] / sW1[tid]) : INFINITY;
    __syncthreads();
    if (tid < 64) {                       // distinct ranks, tie-break by index
        const float t = tjs[tid];
        int rk = 0;
        #pragma unroll 8
        for (int k2 = 0; k2 < 64; k2++) {
            const float tk = tjs[k2];
            rk += (tk < t || (tk == t && k2 < tid)) ? 1 : 0;
        }
        srnk[tid] = rk;
        sknotS[rk] = t;
    }
    __syncthreads();

    // ---- A,B for THIS interval v (same math as harness-verified R5/R6/R7) ----
    if (tid < 64) {
        const int i = tid;
        float cA = 0.0f, cB = b2[i];
        #pragma unroll 8
        for (int j = 0; j < 64; j++) {
            const float w1 = sW1[j];
            const float bb = sb1[j];
            const float w2 = sW2[j * 64 + i];
            if (w1 > 0.0f) {
                if (srnk[j] < v)  { cA = fmaf(w1, w2, cA); cB = fmaf(bb, w2, cB); }
            } else if (w1 < 0.0f) {
                if (srnk[j] >= v) { cA = fmaf(w1, w2, cA); cB = fmaf(bb, w2, cB); }
            } else {
                cB = fmaf(fmaxf(bb, 0.0f), w2, cB);
            }
        }
        sAv[i] = cA; sBv[i] = cB;
    }
    __syncthreads();

    // ---- sub-roots of this interval, ranks, inverse-rank, sorted write ----
    if (tid < 64)
        rroot[tid] = (sAv[tid] != 0.0f) ? (-sBv[tid] / sAv[tid]) : INFINITY;
    __syncthreads();
    if (tid < 64) {
        const float t = rroot[tid];
        int rk = 0;
        #pragma unroll 8
        for (int k2 = 0; k2 < 64; k2++) {
            const float tk = rroot[k2];
            rk += (tk < t || (tk == t && k2 < tid)) ? 1 : 0;
        }
        jinv[rk] = tid;                      // inverse permutation
        ws[WS_SROOT + v * 64 + rk] = t;      // sorted roots for main kernel
    }
    __syncthreads();

    // ---- coefficient rows: wave-parallel prefix over rank-ordered deltas ----
    // lane l owns sub-region s=l+1; its delta is the toggle of unit jinv[l].
    // coef(s) = base + inclusive_prefix(delta)[s-1];  coef(0) = base.
    {
        // per-lane invariants (hoisted out of the o-loop)
        const int   j  = jinv[lane];
        const float Aj = sAv[j], Bj = sBv[j];
        const float tg = (Aj > 0.0f) ? 1.0f : ((Aj < 0.0f) ? -1.0f : 0.0f);
        const float At = Aj * tg, Bt = Bj * tg;        // delta = (At,Bt)*w3[j][o]
        const float Ab = sAv[lane], Bb = sBv[lane];
        const bool  actb = (Ab < 0.0f) || (Ab == 0.0f && Bb > 0.0f);
        const float Abm = actb ? Ab : 0.0f, Bbm = actb ? Bb : 0.0f;
        float* __restrict__ rowbase = ws + WS_COEF + (size_t)(v * 65) * 96;

        for (int o = wv; o < 48; o += 4) {
            const float w3j = sW3[j * 49 + o];         // conflict-free (pad 49)
            const float w3l = sW3[lane * 49 + o];
            float dA = At * w3j, dB = Bt * w3j;        // delta for s=lane+1
            float bA = Abm * w3l, bB = Bbm * w3l;      // base contribution j=lane
            // base: full 64-lane reduce (all lanes end with the total)
            #pragma unroll
            for (int off = 32; off > 0; off >>= 1) {
                bA += __shfl_xor(bA, off);
                bB += __shfl_xor(bB, off);
            }
            // inclusive prefix of deltas over lanes
            #pragma unroll
            for (int off = 1; off < 64; off <<= 1) {
                const float uA = __shfl_up(dA, off);
                const float uB = __shfl_up(dB, off);
                if (lane >= off) { dA += uA; dB += uB; }
            }
            rowbase[(lane + 1) * 96 + 2 * o]     = bA + dA;
            rowbase[(lane + 1) * 96 + 2 * o + 1] = bB + dB;
            if (lane == 0) {
                rowbase[2 * o]     = bA;
                rowbase[2 * o + 1] = bB;
            }
        }
    }

    // ---- block 0: spline tables + sorted outer knots ----
    if (v == 0 && tid < 64) {
        ws[WS_KNOT + tid] = sknotS[tid];

        float vw = theta_w[tid];
        float vh = theta_h[tid];
        float mw = vw, mh = vh;
        #pragma unroll
        for (int off = 32; off > 0; off >>= 1) {
            mw = fmaxf(mw, __shfl_xor(mw, off));
            mh = fmaxf(mh, __shfl_xor(mh, off));
        }
        const float ew = expf(vw - mw);
        const float eh = expf(vh - mh);
        float sumw = ew, sumh = eh;
        #pragma unroll
        for (int off = 32; off > 0; off >>= 1) {
            sumw += __shfl_xor(sumw, off);
            sumh += __shfl_xor(sumh, off);
        }
        float cw = ew / sumw * 2.0f;
        float ch = eh / sumh * 2.0f;
        #pragma unroll
        for (int off = 1; off < 64; off <<= 1) {   // inclusive shfl scan
            const float uw = __shfl_up(cw, off);
            const float uh = __shfl_up(ch, off);
            if (tid >= off) { cw += uw; ch += uh; }
        }
        ws[WS_SXK + 1 + tid] = cw - 1.0f;
        ws[WS_SYK + 1 + tid] = ch - 1.0f;
        if (tid < KS - 1) {
            const float x = theta_d[tid];
            const float sp = (x > 20.0f) ? x : log1pf(expf(x));
            ws[WS_SDK + 1 + tid] = sp + 0.001f;
        }
        if (tid == 0) {
            ws[WS_SXK] = -1.0f;
            ws[WS_SYK] = -1.0f;
            ws[WS_SDK] = 1.0f;
            ws[WS_SDK + KS] = 1.0f;
        }
    }
}

// ---------------------------------------------------------------------------
// FAST-PATH main kernel: EXACT R6 code (harness-verified, 59.5 us, VGPR 32,
// occupancy 63%). R7's full q-unroll regressed it (VGPR 48, occ 42%, 63.4 us)
// -> reverted to #pragma unroll 4.
// ---------------------------------------------------------------------------
__global__ __launch_bounds__(256)
void mobius_spline_kernel(const float* __restrict__ r_in,
                          const float* __restrict__ z_in,
                          const float* __restrict__ ws,
                          float* __restrict__ out,
                          int n)
{
    __shared__ float sxk[KS + 1], syk[KS + 1], sdk[KS + 1];
    __shared__ float sknot[KS];
    __shared__ float sroots[65 * 65];    // stride 65 (odd) -> banks spread

    const int tid = threadIdx.x;

    for (int t2 = tid; t2 < 65; t2 += 256) {
        sxk[t2] = ws[WS_SXK + t2];
        syk[t2] = ws[WS_SYK + t2];
        sdk[t2] = ws[WS_SDK + t2];
    }
    for (int t2 = tid; t2 < 64; t2 += 256) sknot[t2] = ws[WS_KNOT + t2];
    for (int t2 = tid; t2 < 65 * 64; t2 += 256) {
        const int v2 = t2 >> 6, m = t2 & 63;
        sroots[v2 * 65 + m] = ws[WS_SROOT + t2];
    }
    __syncthreads();

    const int idx = blockIdx.x * 256 + tid;
    if (idx >= n) return;

    const float rv = r_in[idx];
    const float zz = z_in[idx];

    // ---------------- spline ----------------
    int lo = 0, hi = KS + 1;
    while (lo < hi) {
        const int mid = (lo + hi) >> 1;
        if (sxk[mid] < rv) lo = mid + 1; else hi = mid;
    }
    int k = lo;
    k = (k == 0) ? 1 : k;
    k = (k == KS + 1) ? KS : k;
    k -= 1;
    const float x_k = sxk[k], x_nk = sxk[k + 1];
    const float y_k = syk[k], y_nk = syk[k + 1];
    const float d_k = sdk[k], d_nk = sdk[k + 1];
    const float rdx = frcp(x_nk - x_k);
    const float dy  = y_nk - y_k;
    const float s_k = dy * rdx;
    const float eps = (rv - x_k) * rdx;
    const float ome = 1.0f - eps;
    const float den = s_k + (d_nk + d_k - 2.0f * s_k) * eps * ome;
    const float rden = frcp(den);
    const float tr  = fmaf(dy * (s_k * eps * eps + d_k * eps * ome), rden, y_k);
    const float dtr = s_k * s_k * (d_nk * eps * eps + 2.0f * s_k * eps * ome + d_k * ome * ome)
                      * rden * rden;

    // ---------------- region lookup: outer interval v, sub-region s ----------
    int lo2 = 0, hi2 = KS;
    while (lo2 < hi2) {
        const int mid = (lo2 + hi2) >> 1;
        if (sknot[mid] < rv) lo2 = mid + 1; else hi2 = mid;
    }
    const int v = lo2;                    // 0..64
    const int rbase = v * 65;
    int lo3 = 0, hi3 = 64;
    while (lo3 < hi3) {
        const int mid = (lo3 + hi3) >> 1;
        if (sroots[rbase + mid] < rv) lo3 = mid + 1; else hi3 = mid;
    }
    const int s = lo3;                    // 0..64

    const float4* __restrict__ row4 =
        (const float4*)(ws + WS_COEF + (size_t)(v * 65 + s) * 96);

    // ---------------- theta logits: th_q = a*rv + b ----------------
    float th[16];
    #pragma unroll
    for (int o8 = 0; o8 < 8; o8++) {
        const float4 c = row4[o8];
        th[2 * o8]     = fmaf(c.x, rv, c.y);
        th[2 * o8 + 1] = fmaf(c.z, rv, c.w);
    }
    float mx = th[0];
    #pragma unroll
    for (int q = 1; q < 16; q++) mx = fmaxf(mx, th[q]);

    float cz, sz;
    __sincosf(zz, &sz, &cz);

    float wsum = 0.0f, tsum = 0.0f, dsum = 0.0f;

    #pragma unroll 4
    for (int q = 0; q < 16; q++) {
        const float4 c = row4[8 + q];     // (a_wx, b_wx, a_wy, b_wy)
        const float rwx = fmaf(c.x, rv, c.y);
        const float rwy = fmaf(c.z, rv, c.w);
        const float nrm = __builtin_amdgcn_sqrtf(rwx * rwx + rwy * rwy);
        const float scl = 0.99f * frcp(1.0f + nrm);
        const float wxx = scl * rwx, wyy = scl * rwy;
        const float wn2 = wxx * wxx + wyy * wyy;
        const float omw = 1.0f - wn2;
        const float dzx = cz - wxx, dzy = sz - wyy;
        const float dn2z = dzx * dzx + dzy * dzy;
        const float cf = omw * frcp(dn2z);
        const float hzx = cf * dzx - wxx;
        const float hzy = cf * dzy - wyy;
        const float d0x = 1.0f - wxx, d0y = -wyy;
        const float dn20 = d0x * d0x + d0y * d0y;
        const float c0 = omw * frcp(dn20);
        const float h0x = c0 * d0x - wxx;
        const float h0y = c0 * d0y - wyy;
        const float cross = hzy * h0x - hzx * h0y;
        const float dotp  = hzx * h0x + hzy * h0y;
        float tx = fast_atan2(cross, dotp);
        tx = (tx >= 0.0f) ? tx : tx + TWO_PI_F;

        const float ew = __expf(th[q] - mx);
        wsum += ew;
        tsum += ew * tx;
        dsum += ew * cf;                  // |dh| = cf exactly
    }

    const float inv = frcp(wsum);
    const float tz  = tsum * inv;
    const float dtz = dsum * inv;
    const float ldj = __logf(dtr) + __logf(dtz);

    out[idx]         = tr;
    out[n + idx]     = tz;
    out[2 * n + idx] = ldj;
}

// ---------------------------------------------------------------------------
// FALLBACK path (workspace too small for coeff table): round-5 kernels,
// harness-verified at 104 us main.
// ---------------------------------------------------------------------------
__global__ __launch_bounds__(256)
void precompute_fb(const float* __restrict__ theta_w,
                   const float* __restrict__ theta_h,
                   const float* __restrict__ theta_d,
                   const float* __restrict__ W1,
                   const float* __restrict__ b1,
                   const float* __restrict__ W2,
                   const float* __restrict__ b2,
                   float* __restrict__ ws)
{
    __shared__ float sW1[64], sb1[64], tjs[64];
    __shared__ int   srnk[64];
    __shared__ float sW2[64 * 64];

    const int tid = threadIdx.x;

    if (tid < 64) {
        const float w1 = W1[tid];
        const float bb = b1[tid];
        sW1[tid] = w1;
        sb1[tid] = bb;
        tjs[tid] = (w1 != 0.0f) ? (-bb / w1) : INFINITY;
    }
    {
        const float4* __restrict__ W2v = (const float4*)W2;
        float4* __restrict__ sW2v = (float4*)sW2;
        for (int t2 = tid; t2 < 1024; t2 += 256) sW2v[t2] = W2v[t2];
    }
    __syncthreads();

    if (tid < 64) {
        const float t = tjs[tid];
        int rk = 0;
        #pragma unroll 8
        for (int k2 = 0; k2 < 64; k2++) {
            const float tk = tjs[k2];
            rk += (tk < t || (tk == t && k2 < tid)) ? 1 : 0;
        }
        srnk[tid] = rk;
    }
    __syncthreads();

    if (blockIdx.x == 0 && tid < 64) {
        ws[WS_KNOT + srnk[tid]] = tjs[tid];
        float vw = theta_w[tid];
        float vh = theta_h[tid];
        float mw = vw, mh = vh;
        #pragma unroll
        for (int off = 32; off > 0; off >>= 1) {
            mw = fmaxf(mw, __shfl_xor(mw, off));
            mh = fmaxf(mh, __shfl_xor(mh, off));
        }
        const float ew = expf(vw - mw);
        const float eh = expf(vh - mh);
        float sumw = ew, sumh = eh;
        #pragma unroll
        for (int off = 32; off > 0; off >>= 1) {
            sumw += __shfl_xor(sumw, off);
            sumh += __shfl_xor(sumh, off);
        }
        float cw = ew / sumw * 2.0f;
        float ch = eh / sumh * 2.0f;
        #pragma unroll
        for (int off = 1; off < 64; off <<= 1) {
            const float uw = __shfl_up(cw, off);
            const float uh = __shfl_up(ch, off);
            if (tid >= off) { cw += uw; ch += uh; }
        }
        ws[WS_SXK + 1 + tid] = cw - 1.0f;
        ws[WS_SYK + 1 + tid] = ch - 1.0f;
        if (tid < KS - 1) {
            const float x = theta_d[tid];
            const float sp = (x > 20.0f) ? x : log1pf(expf(x));
            ws[WS_SDK + 1 + tid] = sp + 0.001f;
        }
        if (tid == 0) {
            ws[WS_SXK] = -1.0f;
            ws[WS_SYK] = -1.0f;
            ws[WS_SDK] = 1.0f;
            ws[WS_SDK + KS] = 1.0f;
        }
    }

    const int p = blockIdx.x * 256 + tid;
    if (p < 65 * 64) {
        const int v = p >> 6;
        const int i = p & 63;
        float cA = 0.0f;
        float cB = b2[i];
        #pragma unroll 8
        for (int j = 0; j < 64; j++) {
            const float w1 = sW1[j];
            const float bb = sb1[j];
            const float w2 = sW2[j * 64 + i];
            if (w1 > 0.0f) {
                if (srnk[j] < v)  { cA = fmaf(w1, w2, cA); cB = fmaf(bb, w2, cB); }
            } else if (w1 < 0.0f) {
                if (srnk[j] >= v) { cA = fmaf(w1, w2, cA); cB = fmaf(bb, w2, cB); }
            } else {
                cB = fmaf(fmaxf(bb, 0.0f), w2, cB);
            }
        }
        ws[WS_A + v * 65 + i] = cA;
        ws[WS_B + v * 65 + i] = cB;
    }
}

__global__ __launch_bounds__(256)
void mobius_spline_fb(const float* __restrict__ r_in,
                      const float* __restrict__ z_in,
                      const float* __restrict__ W3,
                      const float* __restrict__ b3,
                      const float* __restrict__ ws,
                      float* __restrict__ out,
                      int n)
{
    __shared__ float sxk[KS + 1], syk[KS + 1], sdk[KS + 1];
    __shared__ float sknot[KS];
    __shared__ float sA[65 * 65], sB[65 * 65];

    const int tid = threadIdx.x;

    for (int t2 = tid; t2 < 65; t2 += 256) {
        sxk[t2] = ws[WS_SXK + t2];
        syk[t2] = ws[WS_SYK + t2];
        sdk[t2] = ws[WS_SDK + t2];
    }
    for (int t2 = tid; t2 < 64; t2 += 256) sknot[t2] = ws[WS_KNOT + t2];
    for (int t2 = tid; t2 < 4225; t2 += 256) {
        sA[t2] = ws[WS_A + t2];
        sB[t2] = ws[WS_B + t2];
    }
    __syncthreads();

    const int idx = blockIdx.x * 256 + tid;
    if (idx >= n) return;

    const float rv = r_in[idx];
    const float zz = z_in[idx];

    int lo = 0, hi = KS + 1;
    while (lo < hi) {
        const int mid = (lo + hi) >> 1;
        if (sxk[mid] < rv) lo = mid + 1; else hi = mid;
    }
    int k = lo;
    k = (k == 0) ? 1 : k;
    k = (k == KS + 1) ? KS : k;
    k -= 1;
    const float x_k = sxk[k], x_nk = sxk[k + 1];
    const float y_k = syk[k], y_nk = syk[k + 1];
    const float d_k = sdk[k], d_nk = sdk[k + 1];
    const float rdx = frcp(x_nk - x_k);
    const float dy  = y_nk - y_k;
    const float s_k = dy * rdx;
    const float eps = (rv - x_k) * rdx;
    const float ome = 1.0f - eps;
    const float den = s_k + (d_nk + d_k - 2.0f * s_k) * eps * ome;
    const float rden = frcp(den);
    const float tr  = fmaf(dy * (s_k * eps * eps + d_k * eps * ome), rden, y_k);
    const float dtr = s_k * s_k * (d_nk * eps * eps + 2.0f * s_k * eps * ome + d_k * ome * ome)
                      * rden * rden;

    int lo2 = 0, hi2 = KS;
    while (lo2 < hi2) {
        const int mid = (lo2 + hi2) >> 1;
        if (sknot[mid] < rv) lo2 = mid + 1; else hi2 = mid;
    }
    const int abase = lo2 * 65;

    float th[16], wx[16], wy[16];
    #pragma unroll
    for (int q = 0; q < 16; q++) {
        th[q] = b3[q];
        wx[q] = b3[16 + 2 * q];
        wy[q] = b3[17 + 2 * q];
    }

    #pragma unroll 4
    for (int i = 0; i < 64; i++) {
        const float hv = fmaxf(fmaf(rv, sA[abase + i], sB[abase + i]), 0.0f);
        const float* __restrict__ w3r = &W3[i * 48];
        #pragma unroll
        for (int q = 0; q < 16; q++) {
            th[q] = fmaf(hv, w3r[q],          th[q]);
            wx[q] = fmaf(hv, w3r[16 + 2 * q], wx[q]);
            wy[q] = fmaf(hv, w3r[17 + 2 * q], wy[q]);
        }
    }

    float mx = th[0];
    #pragma unroll
    for (int q = 1; q < 16; q++) mx = fmaxf(mx, th[q]);

    float cz, sz;
    __sincosf(zz, &sz, &cz);

    float wsum = 0.0f, tsum = 0.0f, dsum = 0.0f;

    #pragma unroll
    for (int q = 0; q < 16; q++) {
        const float rwx = wx[q], rwy = wy[q];
        const float nrm = __builtin_amdgcn_sqrtf(rwx * rwx + rwy * rwy);
        const float scl = 0.99f * frcp(1.0f + nrm);
        const float wxx = scl * rwx, wyy = scl * rwy;
        const float wn2 = wxx * wxx + wyy * wyy;
        const float omw = 1.0f - wn2;
        const float dzx = cz - wxx, dzy = sz - wyy;
        const float dn2z = dzx * dzx + dzy * dzy;
        const float cf = omw * frcp(dn2z);
        const float hzx = cf * dzx - wxx;
        const float hzy = cf * dzy - wyy;
        const float d0x = 1.0f - wxx, d0y = -wyy;
        const float dn20 = d0x * d0x + d0y * d0y;
        const float c0 = omw * frcp(dn20);
        const float h0x = c0 * d0x - wxx;
        const float h0y = c0 * d0y - wyy;
        const float cross = hzy * h0x - hzx * h0y;
        const float dotp  = hzx * h0x + hzy * h0y;
        float tx = fast_atan2(cross, dotp);
        tx = (tx >= 0.0f) ? tx : tx + TWO_PI_F;

        const float ew = __expf(th[q] - mx);
        wsum += ew;
        tsum += ew * tx;
        dsum += ew * cf;
    }

    const float inv = frcp(wsum);
    const float tz  = tsum * inv;
    const float dtz = dsum * inv;
    const float ldj = __logf(dtr) + __logf(dtz);

    out[idx]         = tr;
    out[n + idx]     = tz;
    out[2 * n + idx] = ldj;
}

extern "C" void kernel_launch(void* const* d_in, const int* in_sizes, int n_in,
                              void* d_out, int out_size, void* d_ws, size_t ws_size,
                              hipStream_t stream) {
    const int n = in_sizes[0];  // 1,000,000
    float* ws = (float*)d_ws;
    const int blocks = (n + 255) / 256;

    if (ws_size >= (size_t)WS_NEED * sizeof(float)) {
        hipLaunchKernelGGL(precompute_full, dim3(65), dim3(256), 0, stream,
                           (const float*)d_in[2], (const float*)d_in[3],
                           (const float*)d_in[4], (const float*)d_in[5],
                           (const float*)d_in[6], (const float*)d_in[7],
                           (const float*)d_in[8], (const float*)d_in[9],
                           (const float*)d_in[10], ws);
        hipLaunchKernelGGL(mobius_spline_kernel, dim3(blocks), dim3(256), 0, stream,
                           (const float*)d_in[0], (const float*)d_in[1],
                           (const float*)ws, (float*)d_out, n);
    } else {
        hipLaunchKernelGGL(precompute_fb, dim3(17), dim3(256), 0, stream,
                           (const float*)d_in[2], (const float*)d_in[3],
                           (const float*)d_in[4], (const float*)d_in[5],
                           (const float*)d_in[6], (const float*)d_in[7],
                           (const float*)d_in[8], ws);
        hipLaunchKernelGGL(mobius_spline_fb, dim3(blocks), dim3(256), 0, stream,
                           (const float*)d_in[0], (const float*)d_in[1],
                           (const float*)d_in[9], (const float*)d_in[10],
                           (const float*)ws, (float*)d_out, n);
    }
}